// Round 8
// baseline (684.300 us; speedup 1.0000x reference)
//
#include <hip/hip_runtime.h>
#include <hip/hip_bf16.h>
#include <math.h>

constexpr int Bc = 2, Lc = 2048, Dc = 1024, Hc = 16, HDc = 64, FFc = 4096;
constexpr int NT = Bc * Lc;              // 4096 tokens
constexpr size_t TD = (size_t)NT * Dc;   // 4194304 elements per [B,L,D] tensor
constexpr size_t MEG = 1024 * 1024;

__device__ __forceinline__ float ldf(const float* p) { return *p; }
__device__ __forceinline__ unsigned short f2b(float f) {
  __hip_bfloat16 h = __float2bfloat16(f);
  return *reinterpret_cast<unsigned short*>(&h);
}

using frag   = __attribute__((ext_vector_type(8))) short;   // 8 bf16 (4 VGPRs)
using f32x4v = __attribute__((ext_vector_type(4))) float;   // MFMA C/D

// async global -> LDS, 16B per lane; LDS dest = wave-uniform base + lane*16
__device__ __forceinline__ void async16(const unsigned short* g, unsigned short* l) {
  __builtin_amdgcn_global_load_lds(
      (const __attribute__((address_space(1))) unsigned int*)g,
      (__attribute__((address_space(3))) unsigned int*)l, 16, 0, 0);
}

// ---------- block reductions (blockDim.x == 256 = 4 waves) ----------
__device__ __forceinline__ float block_sum(float v, float* red) {
  const int lane = threadIdx.x & 63, w = threadIdx.x >> 6;
  #pragma unroll
  for (int o = 32; o > 0; o >>= 1) v += __shfl_down(v, o, 64);
  __syncthreads();
  if (lane == 0) red[w] = v;
  __syncthreads();
  return red[0] + red[1] + red[2] + red[3];
}

// ---------- fp32 -> bf16 convert ----------
__global__ __launch_bounds__(256)
void convert_bf16_kernel(const float* __restrict__ IN, unsigned short* __restrict__ OUT)
{
  const size_t gid = (size_t)blockIdx.x * 256 + threadIdx.x;
  const float4 v = *(const float4*)(IN + gid * 4);
  ushort4 o;
  o.x = f2b(v.x); o.y = f2b(v.y); o.z = f2b(v.z); o.w = f2b(v.w);
  *(ushort4*)(OUT + gid * 4) = o;
}

// ---------- fp32 [R,C] -> bf16 [C,R] transpose-convert (z-batched) ----------
__global__ __launch_bounds__(256)
void transpose_convert_kernel(const float* __restrict__ IN, unsigned short* __restrict__ OUT,
                              int R, int C, long long sIn, long long sOut)
{
  __shared__ float tile[64][65];
  const int t = threadIdx.x;
  const float* in = IN + (long long)blockIdx.z * sIn;
  unsigned short* out = OUT + (long long)blockIdx.z * sOut;
  const int r0 = blockIdx.y * 64, c0 = blockIdx.x * 64;
  #pragma unroll
  for (int i = 0; i < 4; i++) {
    const int r = (t >> 4) + i * 16, c4 = (t & 15) * 4;
    const float4 v = *(const float4*)(in + (size_t)(r0 + r) * C + c0 + c4);
    tile[r][c4+0] = v.x; tile[r][c4+1] = v.y; tile[r][c4+2] = v.z; tile[r][c4+3] = v.w;
  }
  __syncthreads();
  #pragma unroll
  for (int i = 0; i < 4; i++) {
    const int cc = (t >> 4) + i * 16, rr4 = (t & 15) * 4;
    ushort4 o;
    o.x = f2b(tile[rr4+0][cc]); o.y = f2b(tile[rr4+1][cc]);
    o.z = f2b(tile[rr4+2][cc]); o.w = f2b(tile[rr4+3][cc]);
    *(ushort4*)(out + (size_t)(c0 + cc) * R + r0 + rr4) = o;
  }
}

// ---------- fused weight transposes: 10 segments in one launch ----------
struct TPack {
  const float* in[10]; unsigned short* out[10];
  int R[10], C[10], tx[10], start[10];
};
__global__ __launch_bounds__(256)
void fused_transpose_kernel(TPack p)
{
  __shared__ float tile[64][65];
  const int bid = blockIdx.x;
  int s = 0;
  #pragma unroll
  for (int i = 1; i < 10; i++) s = (bid >= p.start[i]) ? i : s;
  const float* in = p.in[s];
  unsigned short* out = p.out[s];
  const int R = p.R[s], C = p.C[s];
  const int local = bid - p.start[s];
  const int bx = local % p.tx[s], by = local / p.tx[s];
  const int r0 = by * 64, c0 = bx * 64;
  const int t = threadIdx.x;
  #pragma unroll
  for (int i = 0; i < 4; i++) {
    const int r = (t >> 4) + i * 16, c4 = (t & 15) * 4;
    const float4 v = *(const float4*)(in + (size_t)(r0 + r) * C + c0 + c4);
    tile[r][c4+0] = v.x; tile[r][c4+1] = v.y; tile[r][c4+2] = v.z; tile[r][c4+3] = v.w;
  }
  __syncthreads();
  #pragma unroll
  for (int i = 0; i < 4; i++) {
    const int cc = (t >> 4) + i * 16, rr4 = (t & 15) * 4;
    ushort4 o;
    o.x = f2b(tile[rr4+0][cc]); o.y = f2b(tile[rr4+1][cc]);
    o.z = f2b(tile[rr4+2][cc]); o.w = f2b(tile[rr4+3][cc]);
    *(ushort4*)(out + (size_t)(c0 + cc) * R + r0 + rr4) = o;
  }
}

// ---------- MFMA bf16 GEMM, double-buffered global_load_lds staging ----------
// C[m,n] = sum_k A[m,k] * Bt[n,k]. Tile BM x 128, BK=32, 2-phase pipeline:
//   stage(t+1 -> buf^1) issued BEFORE compute(t on buf); ONE barrier per iter.
// Swizzle sigma(r) = (r>>1)&3 on staged-source granule and ds_read granule.
constexpr int EPI_BIAS = 0, EPI_BIAS_ROW = 1, EPI_GELU = 2, EPI_ADD = 3, EPI_ADDROW0 = 4,
              EPI_QKV = 5;

template<int BM, int EPI, bool OUTBF, bool OUTBOTH>
__global__ __launch_bounds__(256)
void mfma_gemm_kernel(const unsigned short* __restrict__ A, const unsigned short* __restrict__ Bt,
                      const float* __restrict__ bias, const float* __restrict__ bias2,
                      const float* __restrict__ bias3, const float* __restrict__ extra,
                      float* __restrict__ C, unsigned short* __restrict__ Cbf,
                      int M, int N, int K,
                      long long sA, long long sB, long long sC)
{
  constexpr int NTt = (BM == 128) ? 4 : 2;   // 16-wide n-fragments per wave
  __shared__ unsigned short As[2][BM][4][8];
  __shared__ unsigned short Bs[2][128][4][8];
  const int tid = threadIdx.x;
  const int l = tid & 63, w = tid >> 6;
  const int wm = (BM == 128) ? (w & 1) * 64 : 0;
  const int wn = (BM == 128) ? (w >> 1) * 64 : w * 32;
  const int m0 = blockIdx.y * BM, n0 = blockIdx.x * 128;
  const unsigned short* Ap = A + (long long)blockIdx.z * sA;
  const unsigned short* Bp = Bt + (long long)blockIdx.z * sB;

  f32x4v acc[4][NTt];
  #pragma unroll
  for (int mt = 0; mt < 4; mt++)
    #pragma unroll
    for (int nt = 0; nt < NTt; nt++) acc[mt][nt] = {0.f, 0.f, 0.f, 0.f};

  const int c_ = l >> 4, rm = l & 15;
  int rrB[2], ggB[2];
  #pragma unroll
  for (int j = 0; j < 2; j++) {
    const int chunk = w * 128 + j * 64 + l;
    rrB[j] = chunk >> 2;
    ggB[j] = (chunk & 3) ^ ((rrB[j] >> 1) & 3);
  }
  int rrA = 0, ggA = 0;
  if constexpr (BM == 64) {
    const int chunkA = w * 64 + l;
    rrA = chunkA >> 2;
    ggA = (chunkA & 3) ^ ((rrA >> 1) & 3);
  }

  auto stage = [&](int bi, int k0) {
    if constexpr (BM == 128) {
      #pragma unroll
      for (int j = 0; j < 2; j++) {
        async16(Ap + (size_t)(m0 + rrB[j]) * K + k0 + ggB[j] * 8,
                &As[bi][0][0][0] + (size_t)(w * 128 + j * 64) * 8);
        async16(Bp + (size_t)(n0 + rrB[j]) * K + k0 + ggB[j] * 8,
                &Bs[bi][0][0][0] + (size_t)(w * 128 + j * 64) * 8);
      }
    } else {
      async16(Ap + (size_t)(m0 + rrA) * K + k0 + ggA * 8,
              &As[bi][0][0][0] + (size_t)(w * 64) * 8);
      #pragma unroll
      for (int j = 0; j < 2; j++)
        async16(Bp + (size_t)(n0 + rrB[j]) * K + k0 + ggB[j] * 8,
                &Bs[bi][0][0][0] + (size_t)(w * 128 + j * 64) * 8);
    }
  };

  stage(0, 0);
  __syncthreads();          // vmcnt(0) drain + barrier
  int cur = 0;
  const int sg = (rm >> 1) & 3;

  for (int k0 = 0; k0 < K; k0 += 32) {
    if (k0 + 32 < K) stage(cur ^ 1, k0 + 32);   // prefetch next tile (other buffer)

    frag af[4], bfr[NTt];
    #pragma unroll
    for (int mt = 0; mt < 4; mt++)
      af[mt] = *(const frag*)&As[cur][wm + mt * 16 + rm][c_ ^ sg][0];
    #pragma unroll
    for (int nt = 0; nt < NTt; nt++)
      bfr[nt] = *(const frag*)&Bs[cur][wn + nt * 16 + rm][c_ ^ sg][0];
    #pragma unroll
    for (int mt = 0; mt < 4; mt++)
      #pragma unroll
      for (int nt = 0; nt < NTt; nt++)
        acc[mt][nt] = __builtin_amdgcn_mfma_f32_16x16x32_bf16(af[mt], bfr[nt], acc[mt][nt], 0, 0, 0);

    __syncthreads();        // drains this iter's lgkm reads + next-tile vmcnt
    cur ^= 1;
  }

  float* Cp = C + (long long)blockIdx.z * sC;
  unsigned short* Cbp = Cbf + (long long)blockIdx.z * sC;
  #pragma unroll
  for (int mt = 0; mt < 4; mt++) {
    #pragma unroll
    for (int nt = 0; nt < NTt; nt++) {
      const int mq = m0 + wm + mt * 16 + c_ * 4;   // quad-base row (i = 0..3 below)
      const int n  = n0 + wn + nt * 16 + rm;       // C/D: col=lane&15
      if constexpr (EPI == EPI_QKV) {
        // n in [0,1024): q (fp32) | [1024,2048): k (fp32) | [2048,3072): V^T bf16
        const float* bp = (n < 1024) ? bias : ((n < 2048) ? bias2 : bias3);
        const float bv_ = ldf(bp + (n & 1023));
        const float r0 = acc[mt][nt][0] + bv_;
        const float r1 = acc[mt][nt][1] + bv_;
        const float r2 = acc[mt][nt][2] + bv_;
        const float r3 = acc[mt][nt][3] + bv_;
        if (n < 2048) {
          float* dst = Cp + (size_t)(n >> 10) * TD + (size_t)mq * Dc + (n & 1023);
          dst[0] = r0; dst[Dc] = r1; dst[2 * Dc] = r2; dst[3 * Dc] = r3;
        } else {
          ushort4 o;
          o.x = f2b(r0); o.y = f2b(r1); o.z = f2b(r2); o.w = f2b(r3);
          *(ushort4*)(Cbp + (size_t)(mq >> 11) * ((size_t)Lc * Dc)
                      + (size_t)(n - 2048) * Lc + (mq & (Lc - 1))) = o;
        }
      } else {
        #pragma unroll
        for (int i = 0; i < 4; i++) {
          const int m = mq + i;                     // C/D: row=(lane>>4)*4+reg
          float r = acc[mt][nt][i];
          if constexpr (EPI == EPI_BIAS || EPI == EPI_GELU || EPI == EPI_ADD || EPI == EPI_ADDROW0)
            r += ldf(bias + n);
          if constexpr (EPI == EPI_BIAS_ROW) r += ldf(bias + m);
          if constexpr (EPI == EPI_GELU)
            r = 0.5f * r * (1.0f + erff(r * 0.70710678118654752f));
          if constexpr (EPI == EPI_ADD) r += extra[(size_t)m * N + n];
          if constexpr (EPI == EPI_ADDROW0) r += extra[(size_t)(m >> 11) * ((size_t)Lc * Dc) + n];
          if constexpr (OUTBOTH) { Cp[(size_t)m * N + n] = r; Cbp[(size_t)m * N + n] = f2b(r); }
          else if constexpr (OUTBF) Cbp[(size_t)m * N + n] = f2b(r);
          else                      Cp[(size_t)m * N + n] = r;
        }
      }
    }
  }
}

// ---------- RoPE table fill ----------
__global__ __launch_bounds__(256)
void pe_fill_kernel(float* __restrict__ pet)
{
  const int gid = blockIdx.x * 256 + threadIdx.x;  // Lc*64
  const int l = gid >> 6, t = gid & 63;
  const int j = t & 31;
  const float wj = exp2f(-(float)j * (13.2877123795494f / 32.0f));
  const float ang = (float)l * wj;
  pet[gid] = (t < 32) ? cosf(ang) : sinf(ang);
}

// ---------- fused RoPE for Q and K: fp32 in, bf16 out ----------
// Q is pre-scaled by 0.125*log2(e) so flash-attn softmax works in base-2
// with zero per-element scale ops.
__global__ __launch_bounds__(256)
void rope2_kernel(const float* __restrict__ Qi, const float* __restrict__ Ki,
                  const float* __restrict__ pet,
                  unsigned short* __restrict__ Qo, unsigned short* __restrict__ Ko)
{
  int gid = blockIdx.x * 256 + threadIdx.x;  // 2*NT*Hc
  const int sel = gid >= NT * Hc;            // block-uniform (NT*Hc % 256 == 0)
  if (sel) gid -= NT * Hc;
  const float* X = sel ? Ki : Qi;
  unsigned short* O = sel ? Ko : Qo;
  const float scl = sel ? 1.0f : 0.125f * 1.44269504f;
  const int h = gid & (Hc - 1);
  const int token = gid >> 4;
  const int l = token & (Lc - 1);
  const float* p = X + (size_t)token * Dc + h * HDc;
  unsigned short* po = O + (size_t)token * Dc + h * HDc;
  const float* pr = pet + l * 64;
  float x[64], out[64];
  #pragma unroll
  for (int i = 0; i < 16; i++) *(float4*)&x[4*i] = *(const float4*)&p[4*i];
  #pragma unroll
  for (int u = 0; u < 32; u++) {
    const int base = (u < 16) ? (2 * u) : (32 + 2 * (u - 16));
    const float c = pr[base], s = pr[base + 1];
    out[u]      = (x[2*u] * c - x[2*u+1] * s) * scl;
    out[32 + u] = (x[2*u] * s + x[2*u+1] * c) * scl;
  }
  #pragma unroll
  for (int i = 0; i < 16; i++) {
    ushort4 o;
    o.x = f2b(out[4*i+0]); o.y = f2b(out[4*i+1]);
    o.z = f2b(out[4*i+2]); o.w = f2b(out[4*i+3]);
    *(ushort4*)&po[4*i] = o;
  }
}

// ---------- per-tile max row-norm of Q (scaled) and K, from the bf16 data ----------
// grid (32 tiles, 32 bh, z: 0=K 1=Q); out[bh*32+tile] = max_row ||row||_2.
// Feeds the flash kernel's Cauchy-Schwarz tile bound.
__global__ __launch_bounds__(256)
void tile_norm_kernel(const unsigned short* __restrict__ Qb,
                      const unsigned short* __restrict__ Kb,
                      float* __restrict__ qnb, float* __restrict__ knb)
{
  __shared__ float red[4];
  const int tile = blockIdx.x, bh = blockIdx.y;
  const int b = bh >> 4, h = bh & 15;
  const unsigned short* X = blockIdx.z ? Qb : Kb;
  const int tid = threadIdx.x;
  const int row = tid >> 2, seg = tid & 3;
  const unsigned short* p = X + ((size_t)(b * Lc + tile * 64 + row)) * Dc + h * 64 + seg * 16;
  const uint4 v0 = *(const uint4*)p;
  const uint4 v1 = *(const uint4*)(p + 8);
  const unsigned int vv[8] = {v0.x, v0.y, v0.z, v0.w, v1.x, v1.y, v1.z, v1.w};
  float ss = 0.f;
  #pragma unroll
  for (int i = 0; i < 8; i++) {
    const float a = __uint_as_float(vv[i] << 16);
    const float c = __uint_as_float(vv[i] & 0xffff0000u);
    ss = fmaf(a, a, ss); ss = fmaf(c, c, ss);
  }
  ss += __shfl_xor(ss, 1, 64);
  ss += __shfl_xor(ss, 2, 64);          // all 4 lanes of a row-group: full row sumsq
  float mx = ss;
  mx = fmaxf(mx, __shfl_xor(mx, 4, 64));
  mx = fmaxf(mx, __shfl_xor(mx, 8, 64));
  mx = fmaxf(mx, __shfl_xor(mx, 16, 64));
  mx = fmaxf(mx, __shfl_xor(mx, 32, 64));
  if ((tid & 63) == 0) red[tid >> 6] = mx;
  __syncthreads();
  if (tid == 0) {
    const float r = fmaxf(fmaxf(red[0], red[1]), fmaxf(red[2], red[3]));
    (blockIdx.z ? qnb : knb)[bh * 32 + tile] = sqrtf(r);
  }
}

// ---------- MFMA flash attention v8 ----------
// One block = 64 q-rows x one (b,h); 4 waves x 16 q-rows. v5 2-deep dbuf
// structure (v7's 3-buf counted-vmcnt regressed: occupancy loss > pipeline
// gain). NEW: bound-based tile skip BEFORE staging. By Cauchy-Schwarz,
// tmax(tile u) <= qnmax*kn[u] + sl2*max(q0+63-64u,0). If that bound <
// min_rows(m_i) - 27, the tile contributes < 2048*2^-27 ~ 1.5e-5 and is
// skipped ENTIRELY (no staging, no QK^T, no softmax, no PV). Decision is
// monotone-safe (m_i only grows). Runtime skip (actual tmax) kept as the
// second layer for staged tiles.
__global__ __launch_bounds__(256)
void flash_attn_mfma_kernel(const unsigned short* __restrict__ Q,
                            const unsigned short* __restrict__ K,
                            const unsigned short* __restrict__ VT,
                            const float* __restrict__ qnb,
                            const float* __restrict__ knb,
                            unsigned short* __restrict__ O)
{
  __shared__ unsigned short Qs[64][8][8];
  __shared__ unsigned short Ks[2][64][8][8];
  __shared__ unsigned short Vt[2][64][8][8];
  __shared__ unsigned short Ps[64][72];
  __shared__ float knS[32];
  __shared__ float mS[64];
  const int tid = threadIdx.x;
  const int l = tid & 63, w = tid >> 6;
  const int lg = l >> 4, lm = l & 15;
  const int q0 = blockIdx.x * 64;
  const int bh = blockIdx.y;
  const int b = bh >> 4, h = bh & 15;
  const size_t rowbase = (size_t)b * Lc;
  const size_t vbase = (size_t)b * Lc * Dc;
  const int dbase = h * 64;
  const float sl2 = exp2f(-0.5f * (float)h) * 1.44269504f; // slope * log2(e)

  auto stageKV = [&](int bi, int k0s) {
    #pragma unroll
    for (int j = 0; j < 2; j++) {
      const int chunk = (w * 2 + j) * 64 + l;
      const int r = chunk >> 3, gsrc = (chunk & 7) ^ (r & 7);
      async16(K + (rowbase + k0s + r) * Dc + dbase + gsrc * 8,
              &Ks[bi][0][0][0] + (size_t)chunk * 8);
      async16(VT + vbase + (size_t)(dbase + r) * Lc + k0s + gsrc * 8,
              &Vt[bi][0][0][0] + (size_t)chunk * 8);
    }
  };

  // ---- stage Q + first K/V tile; load norms ----
  #pragma unroll
  for (int j = 0; j < 2; j++) {
    const int chunk = (w * 2 + j) * 64 + l;
    const int r = chunk >> 3, gsrc = (chunk & 7) ^ (r & 7);
    async16(Q + (rowbase + q0 + r) * Dc + dbase + gsrc * 8,
            &Qs[0][0][0] + (size_t)chunk * 8);
  }
  stageKV(0, 0);
  const float qmx = qnb[bh * 32 + blockIdx.x] * 1.01f;  // slack for fp32 norm rounding
  if (tid < 32) knS[tid] = knb[bh * 32 + tid];
  if (tid < 64) mS[tid] = -3.0e38f;
  __syncthreads();
  frag qf[2];
  #pragma unroll
  for (int s = 0; s < 2; s++)
    qf[s] = *(const frag*)&Qs[w * 16 + lm][(s * 4 + lg) ^ (lm & 7)][0];

  // per-lane constants
  const float qg = (float)(q0 + w * 16 + lm);
  float koff[4][4];
  #pragma unroll
  for (int kt = 0; kt < 4; kt++)
    #pragma unroll
    for (int i = 0; i < 4; i++) koff[kt][i] = (float)(kt * 16 + lg * 4 + i);

  float m_i = -3.0e38f, l_i = 0.f;
  f32x4v acc_o[4];
  #pragma unroll
  for (int dt = 0; dt < 4; dt++) acc_o[dt] = {0.f, 0.f, 0.f, 0.f};

  int nslot = 1;                         // slot for the next staged tile
  bool staged_cur = true; int slot_cur = 0;   // tile 0 staged in slot 0
  bool staged_next = false; int slot_next = 0;

  for (int t = 0; t < Lc / 64; ++t) {
    const int k0 = t * 64;

    // ---- block-uniform running min of m over all 64 rows ----
    float mb = mS[l];
    mb = fminf(mb, __shfl_xor(mb, 1, 64));
    mb = fminf(mb, __shfl_xor(mb, 2, 64));
    mb = fminf(mb, __shfl_xor(mb, 4, 64));
    mb = fminf(mb, __shfl_xor(mb, 8, 64));
    mb = fminf(mb, __shfl_xor(mb, 16, 64));
    mb = fminf(mb, __shfl_xor(mb, 32, 64));

    // ---- bound-skip decision + conditional staging of tile t+1 ----
    if (t + 1 < Lc / 64) {
      const int u = t + 1;
      const float biasmax = sl2 * fmaxf((float)(q0 + 63 - 64 * u), 0.f);
      staged_next = (qmx * knS[u] + biasmax) >= mb - 27.0f;
      if (staged_next) { slot_next = nslot; stageKV(nslot, u * 64); nslot ^= 1; }
    } else staged_next = false;

    if (staged_cur) {
      // ---- S^T = K Q^T : rows k (64), cols q (16 of this wave) ----
      f32x4v st[4];
      #pragma unroll
      for (int kt = 0; kt < 4; kt++) st[kt] = {0.f, 0.f, 0.f, 0.f};
      __builtin_amdgcn_s_setprio(1);
      #pragma unroll
      for (int kt = 0; kt < 4; kt++) {
        #pragma unroll
        for (int s = 0; s < 2; s++) {
          frag kf = *(const frag*)&Ks[slot_cur][kt * 16 + lm][(s * 4 + lg) ^ (lm & 7)][0];
          st[kt] = __builtin_amdgcn_mfma_f32_16x16x32_bf16(kf, qf[s], st[kt], 0, 0, 0);
        }
      }
      __builtin_amdgcn_s_setprio(0);

      // ---- bias by region (block-uniform branch) + row max ----
      const float qk0 = qg - (float)k0;
      float sv[4][4], tmax = -3.0e38f;
      if (k0 + 64 <= q0) {           // fully past: bias = sl2*(qg-kg), linear
        #pragma unroll
        for (int kt = 0; kt < 4; kt++)
          #pragma unroll
          for (int i = 0; i < 4; i++) {
            const float v = fmaf(sl2, qk0 - koff[kt][i], st[kt][i]);
            sv[kt][i] = v; tmax = fmaxf(tmax, v);
          }
      } else if (k0 <= q0) {         // diagonal tile: clamp at 0
        #pragma unroll
        for (int kt = 0; kt < 4; kt++)
          #pragma unroll
          for (int i = 0; i < 4; i++) {
            const float v = fmaf(sl2, fmaxf(qk0 - koff[kt][i], 0.f), st[kt][i]);
            sv[kt][i] = v; tmax = fmaxf(tmax, v);
          }
      } else {                       // fully future: bias = 0
        #pragma unroll
        for (int kt = 0; kt < 4; kt++)
          #pragma unroll
          for (int i = 0; i < 4; i++) {
            const float v = st[kt][i];
            sv[kt][i] = v; tmax = fmaxf(tmax, v);
          }
      }
      tmax = fmaxf(tmax, __shfl_xor(tmax, 16, 64));
      tmax = fmaxf(tmax, __shfl_xor(tmax, 32, 64));

      // ---- runtime tile skip (second layer) ----
      if (!__all(tmax < m_i - 27.0f)) {
        if (__any(tmax > m_i)) {     // exact skip: otherwise alpha == 1
          const float mnew = fmaxf(m_i, tmax);
          const float alpha = exp2f(m_i - mnew);
          m_i = mnew;
          l_i *= alpha;
          float aO[4];
          #pragma unroll
          for (int i = 0; i < 4; i++) aO[i] = __shfl(alpha, lg * 4 + i, 64);
          #pragma unroll
          for (int dt = 0; dt < 4; dt++)
            #pragma unroll
            for (int i = 0; i < 4; i++) acc_o[dt][i] *= aO[i];
        }
        float rsum = 0.f;
        const int qrow = w * 16 + lm;
        #pragma unroll
        for (int kt = 0; kt < 4; kt++) {
          const float p0 = exp2f(sv[kt][0] - m_i), p1 = exp2f(sv[kt][1] - m_i);
          const float p2 = exp2f(sv[kt][2] - m_i), p3 = exp2f(sv[kt][3] - m_i);
          rsum += (p0 + p1) + (p2 + p3);
          unsigned int w0, w1;       // packed bf16 pairs (lo=first arg)
          asm("v_cvt_pk_bf16_f32 %0, %1, %2" : "=v"(w0) : "v"(p0), "v"(p1));
          asm("v_cvt_pk_bf16_f32 %0, %1, %2" : "=v"(w1) : "v"(p2), "v"(p3));
          uint2 pw; pw.x = w0; pw.y = w1;
          *(uint2*)&Ps[qrow][kt * 16 + lg * 4] = pw;   // 4 consecutive k
        }
        rsum += __shfl_xor(rsum, 16, 64);
        rsum += __shfl_xor(rsum, 32, 64);
        l_i += rsum;

        // ---- O += P V (Ps rows wave-private) ----
        __builtin_amdgcn_s_setprio(1);
        #pragma unroll
        for (int c = 0; c < 2; c++) {
          frag ap = *(const frag*)&Ps[w * 16 + lm][c * 32 + lg * 8];
          #pragma unroll
          for (int dt = 0; dt < 4; dt++) {
            frag bv = *(const frag*)&Vt[slot_cur][dt * 16 + lm][(c * 4 + lg) ^ (lm & 7)][0];
            acc_o[dt] = __builtin_amdgcn_mfma_f32_16x16x32_bf16(ap, bv, acc_o[dt], 0, 0, 0);
          }
        }
        __builtin_amdgcn_s_setprio(0);
      }
      if (lg == 0) mS[w * 16 + lm] = m_i;   // publish running max for block-min
    }

    __syncthreads();    // drains staged loads + this iter's LDS reads
    staged_cur = staged_next; slot_cur = slot_next;
  }

  // ---- epilogue: normalize, bounce through Ps, coalesced store ----
  float lO[4];
  #pragma unroll
  for (int i = 0; i < 4; i++) lO[i] = 1.0f / __shfl(l_i, lg * 4 + i, 64);
  #pragma unroll
  for (int dt = 0; dt < 4; dt++)
    #pragma unroll
    for (int i = 0; i < 4; i++)
      Ps[w * 16 + lg * 4 + i][dt * 16 + lm] = f2b(acc_o[dt][i] * lO[i]);
  __syncthreads();
  #pragma unroll
  for (int j = 0; j < 2; j++) {
    const int chunk = (w * 2 + j) * 64 + l;
    const int r = chunk >> 3, g = chunk & 7;
    alignas(16) unsigned short tmp[8];
    #pragma unroll
    for (int t = 0; t < 8; t++) tmp[t] = Ps[r][g * 8 + t];
    *(uint4*)(O + (rowbase + q0 + r) * Dc + dbase + g * 8) = *(uint4*)tmp;
  }
}

// ---------- fused: mem1 = RES + ln(X;n1) -> fp32; hln = ln(mem1;cln) -> bf16 ----
__global__ __launch_bounds__(256)
void ln_res_cln_kernel(const float* __restrict__ X, const float* __restrict__ RES,
                       const float* __restrict__ g1, const float* __restrict__ b1,
                       const float* __restrict__ g2, const float* __restrict__ b2,
                       float* __restrict__ OUT1, unsigned short* __restrict__ OUT2)
{
  __shared__ float red4[4];
  const int row = blockIdx.x, tid = threadIdx.x;
  const size_t base = (size_t)row * Dc + tid * 4;
  const float4 xv = *(const float4*)(X + base);
  float s = xv.x + xv.y + xv.z + xv.w;
  s = block_sum(s, red4);
  const float mean = s * (1.0f / Dc);
  const float d0 = xv.x-mean, d1 = xv.y-mean, d2 = xv.z-mean, d3 = xv.w-mean;
  float ss = d0*d0 + d1*d1 + d2*d2 + d3*d3;
  ss = block_sum(ss, red4);
  const float rstd = rsqrtf(ss * (1.0f / Dc) + 1e-5f);
  const int c = tid * 4;
  const float4 rv = *(const float4*)(RES + base);
  float y0 = rv.x + d0*rstd*ldf(g1+c+0) + ldf(b1+c+0);
  float y1 = rv.y + d1*rstd*ldf(g1+c+1) + ldf(b1+c+1);
  float y2 = rv.z + d2*rstd*ldf(g1+c+2) + ldf(b1+c+2);
  float y3 = rv.w + d3*rstd*ldf(g1+c+3) + ldf(b1+c+3);
  *(float4*)(OUT1 + base) = make_float4(y0, y1, y2, y3);
  float s2 = y0 + y1 + y2 + y3;
  s2 = block_sum(s2, red4);
  const float mean2 = s2 * (1.0f / Dc);
  const float e0 = y0-mean2, e1 = y1-mean2, e2 = y2-mean2, e3 = y3-mean2;
  float ss2 = e0*e0 + e1*e1 + e2*e2 + e3*e3;
  ss2 = block_sum(ss2, red4);
  const float rstd2 = rsqrtf(ss2 * (1.0f / Dc) + 1e-5f);
  ushort4 o;
  o.x = f2b(e0*rstd2*ldf(g2+c+0) + ldf(b2+c+0));
  o.y = f2b(e1*rstd2*ldf(g2+c+1) + ldf(b2+c+1));
  o.z = f2b(e2*rstd2*ldf(g2+c+2) + ldf(b2+c+2));
  o.w = f2b(e3*rstd2*ldf(g2+c+3) + ldf(b2+c+3));
  *(ushort4*)(OUT2 + base) = o;
}

__global__ __launch_bounds__(256)   // OUT = ln(X + Y)
void ln_sum_kernel(const float* __restrict__ X, const float* __restrict__ Y,
                   const float* __restrict__ g, const float* __restrict__ be,
                   float* __restrict__ OUT)
{
  __shared__ float red4[4];
  const int row = blockIdx.x, tid = threadIdx.x;
  const size_t base = (size_t)row * Dc + tid * 4;
  const float4 xv = *(const float4*)(X + base);
  const float4 yv = *(const float4*)(Y + base);
  const float x0 = xv.x+yv.x, x1 = xv.y+yv.y, x2 = xv.z+yv.z, x3 = xv.w+yv.w;
  float s = x0 + x1 + x2 + x3;
  s = block_sum(s, red4);
  const float mean = s * (1.0f / Dc);
  const float d0 = x0-mean, d1 = x1-mean, d2 = x2-mean, d3 = x3-mean;
  float ss = d0*d0 + d1*d1 + d2*d2 + d3*d3;
  ss = block_sum(ss, red4);
  const float rstd = rsqrtf(ss * (1.0f / Dc) + 1e-5f);
  const int c = tid * 4;
  float4 o;
  o.x = d0*rstd*ldf(g+c+0) + ldf(be+c+0);
  o.y = d1*rstd*ldf(g+c+1) + ldf(be+c+1);
  o.z = d2*rstd*ldf(g+c+2) + ldf(be+c+2);
  o.w = d3*rstd*ldf(g+c+3) + ldf(be+c+3);
  *(float4*)(OUT + base) = o;
}

// ---------- GLU ----------
__global__ __launch_bounds__(256)
void glu_kernel(const float* __restrict__ H1, float* __restrict__ HG)
{
  const int gid = blockIdx.x * 256 + threadIdx.x;
  const int t = gid >> 8;
  const int c4 = (gid & 255) * 4;
  const float* p = H1 + (size_t)t * (2 * Dc);
  const float4 a = *(const float4*)(p + c4);
  const float4 gg = *(const float4*)(p + Dc + c4);
  float4 o;
  o.x = a.x / (1.0f + expf(-gg.x));
  o.y = a.y / (1.0f + expf(-gg.y));
  o.z = a.z / (1.0f + expf(-gg.z));
  o.w = a.w / (1.0f + expf(-gg.w));
  *(float4*)(HG + (size_t)t * Dc + c4) = o;
}

// ---------- depthwise conv K=5 (+bias, bn-scale, hardswish), bf16 out ----------
__global__ __launch_bounds__(256)
void dwconv_bf16_kernel(const float* __restrict__ HG, const float* __restrict__ w,
                        const float* __restrict__ wb, const float* __restrict__ gn,
                        const float* __restrict__ bb, unsigned short* __restrict__ OUT)
{
  const int gid = blockIdx.x * 256 + threadIdx.x;
  const int d = gid & (Dc - 1);
  const int l = (gid >> 10) & (Lc - 1);
  const int b = gid >> 21;
  const size_t rowb = (size_t)b * Lc;
  float acc = ldf(wb + d);
  #pragma unroll
  for (int s = 0; s < 5; s++) {
    const int lp = l + 2 - s;
    if (lp >= 0 && lp < Lc)
      acc += ldf(w + d * 5 + s) * HG[((rowb + lp) << 10) + d];
  }
  const float rs = rsqrtf(1.0f + 1e-5f);
  const float t = acc * rs * ldf(gn + d) + ldf(bb + d);
  OUT[gid] = f2b(t * fminf(fmaxf(t + 3.0f, 0.0f), 6.0f) * (1.0f / 6.0f));
}

// =====================================================================
extern "C" void kernel_launch(void* const* d_in, const int* in_sizes, int n_in,
                              void* d_out, int out_size, void* d_ws, size_t ws_size,
                              hipStream_t stream) {
  (void)in_sizes; (void)n_in; (void)out_size; (void)ws_size;
  const float* mem    = (const float*)d_in[0];
  const float* wq     = (const float*)d_in[1];
  const float* bq     = (const float*)d_in[2];
  const float* wk     = (const float*)d_in[3];
  const float* bk     = (const float*)d_in[4];
  const float* wv     = (const float*)d_in[5];
  const float* bv     = (const float*)d_in[6];
  const float* wo     = (const float*)d_in[7];
  const float* bo     = (const float*)d_in[8];
  const float* n1g    = (const float*)d_in[9];
  const float* n1b    = (const float*)d_in[10];
  const float* clng   = (const float*)d_in[11];
  const float* clnb   = (const float*)d_in[12];
  const float* pw1w   = (const float*)d_in[13];
  const float* pw1b   = (const float*)d_in[14];
  const float* dww    = (const float*)d_in[15];
  const float* dwb    = (const float*)d_in[16];
  const float* bng    = (const float*)d_in[17];
  const float* bnb    = (const float*)d_in[18];
  const float* pw2w   = (const float*)d_in[19];
  const float* pw2b   = (const float*)d_in[20];
  const float* projw  = (const float*)d_in[21];
  const float* projb  = (const float*)d_in[22];
  const float* proj2w = (const float*)d_in[23];
  const float* proj2b = (const float*)d_in[24];
  const float* lin1w  = (const float*)d_in[25];
  const float* lin1b  = (const float*)d_in[26];
  const float* lin2w  = (const float*)d_in[27];
  const float* lin2b  = (const float*)d_in[28];
  const float* n3g    = (const float*)d_in[29];
  const float* n3b    = (const float*)d_in[30];
  float* out = (float*)d_out;

  char* base = (char*)d_ws;
  float* qb   = (float*)base;          // q fp32 -> tgt2 fp32
  float* kb   = qb + TD;               // k fp32 -> mem1
  float* big1 = kb + TD;               // h1 lo -> mem2 fp32
  float* big2 = big1 + TD;             // h1 hi -> conv_out
  float* ob   = big2 + TD;             // hg -> ffout
  unsigned short* abf  = (unsigned short*)(base + 5 * TD * 4);  // bf16 hub
  unsigned short* qbf  = abf + TD;     // rope-q -> mem2 bf16
  unsigned short* kbf  = qbf + TD;
  unsigned short* vtb  = kbf + TD;     // V^T bf16  [b][1024 d][2048 l]
  unsigned short* m1T  = vtb + TD;
  unsigned short* ffbbf= m1T + TD;     // NT*FF = 4*TD shorts
  unsigned short* wt   = ffbbf + 4 * TD;
  unsigned short* wqT    = wt;            // [1024][1024] } contiguous => [3072][1024] fused QKV B^T
  unsigned short* wkT    = wqT + MEG;
  unsigned short* wvT    = wkT + MEG;
  unsigned short* woT    = wvT + MEG;
  unsigned short* pw1T   = woT + MEG;     // [2048][1024]
  unsigned short* pw2T   = pw1T + 2*MEG;  // [1024][1024]
  unsigned short* proj2T = pw2T + MEG;    // [1024][1024]
  unsigned short* projwT = proj2T + MEG;  // [2048][2048]
  unsigned short* lin1T  = projwT + 4*MEG;// [4096][1024]
  unsigned short* lin2T  = lin1T + 4*MEG; // [1024][4096]
  float* pet = (float*)(lin2T + 4*MEG);   // [2048][64] rope table
  float* knb = pet + (size_t)Lc * 64;     // [32 bh][32 tiles] K max row-norm
  float* qnb = knb + 1024;                // [32 bh][32 qblocks] Q max row-norm

  const dim3 blk(256);
  const long long LD = (long long)Lc * Dc;

  // ---- fused weight transposes + rope table ----
  TPack tp;
  const float* tin[10]  = {wq, wk, wv, wo, pw1w, pw2w, proj2w, projw, lin1w, lin2w};
  unsigned short* tout[10] = {wqT, wkT, wvT, woT, pw1T, pw2T, proj2T, projwT, lin1T, lin2T};
  const int tR[10] = {1024,1024,1024,1024,1024,1024,1024,2048,1024,4096};
  const int tC[10] = {1024,1024,1024,1024,2048,1024,1024,2048,4096,1024};
  int startAcc = 0;
  for (int i = 0; i < 10; i++) {
    tp.in[i] = tin[i]; tp.out[i] = tout[i];
    tp.R[i] = tR[i]; tp.C[i] = tC[i]; tp.tx[i] = tC[i] / 64;
    tp.start[i] = startAcc;
    startAcc += (tR[i] / 64) * (tC[i] / 64);
  }
  fused_transpose_kernel<<<dim3(startAcc), blk, 0, stream>>>(tp);
  pe_fill_kernel<<<dim3(Lc * 64 / 256), blk, 0, stream>>>(pet);

  // ---- attention ----
  convert_bf16_kernel<<<dim3((unsigned)(TD/1024)),blk,0,stream>>>(mem, abf);
  // fused QKV: N=3072, q->qb fp32, k->kb fp32, V->vtb transposed bf16 directly
  mfma_gemm_kernel<128,EPI_QKV,false,false><<<dim3(24,32,1),blk,0,stream>>>(
      abf, wqT, bq, bk, bv, nullptr, qb, vtb, NT, 3*Dc, Dc, 0, 0, 0);
  rope2_kernel<<<dim3(2*NT*Hc/256),blk,0,stream>>>(qb, kb, pet, qbf, kbf);
  tile_norm_kernel<<<dim3(32,32,2),blk,0,stream>>>(qbf, kbf, qnb, knb);
  flash_attn_mfma_kernel<<<dim3(Lc/64, Bc*Hc),blk,0,stream>>>(qbf,kbf,vtb,qnb,knb,abf);
  mfma_gemm_kernel<64,EPI_BIAS,false,false><<<dim3(8,64,1),blk,0,stream>>>(
      abf,woT,bo,nullptr,nullptr,nullptr,qb,nullptr,NT,Dc,Dc,0,0,0);
  // mem1 (fp32 -> kb) and ln(mem1) (bf16 -> abf) in one pass
  ln_res_cln_kernel<<<dim3(NT),blk,0,stream>>>(qb, mem, n1g, n1b, clng, clnb, kb, abf);

  // ---- conv block ----
  mfma_gemm_kernel<128,EPI_BIAS,false,false><<<dim3(16,32,1),blk,0,stream>>>(
      abf,pw1T,pw1b,nullptr,nullptr,nullptr,big1,nullptr,NT,2*Dc,Dc,0,0,0);
  glu_kernel<<<dim3((unsigned)(TD/4/256)),blk,0,stream>>>(big1, ob);
  dwconv_bf16_kernel<<<dim3((unsigned)(TD/256)),blk,0,stream>>>(ob, dww, dwb, bng, bnb, abf);
  mfma_gemm_kernel<64,EPI_ADDROW0,false,false><<<dim3(8,64,1),blk,0,stream>>>(
      abf,pw2T,pw2b,nullptr,nullptr,kb,big2,nullptr,NT,Dc,Dc,0,0,0);

  // ---- proj path ----
  transpose_convert_kernel<<<dim3(16,32,2),blk,0,stream>>>(kb, m1T, 2048, 1024, LD, LD);
  mfma_gemm_kernel<64,EPI_BIAS_ROW,true,false><<<dim3(8,32,2),blk,0,stream>>>(
      projwT,m1T,projb,nullptr,nullptr,nullptr,nullptr,abf,Lc,Dc,Lc,0,LD,LD);
  // mem2 = proj@proj2 + conv_out: fp32 -> big1 AND bf16 -> qbf (feeds lin1)
  mfma_gemm_kernel<64,EPI_ADD,false,true><<<dim3(8,64,1),blk,0,stream>>>(
      abf,proj2T,proj2b,nullptr,nullptr,big2,big1,qbf,NT,Dc,Dc,0,0,0);

  // ---- feed-forward ----
  mfma_gemm_kernel<128,EPI_GELU,true,false><<<dim3(32,32,1),blk,0,stream>>>(
      qbf,lin1T,lin1b,nullptr,nullptr,nullptr,nullptr,ffbbf,NT,FFc,Dc,0,0,0);
  mfma_gemm_kernel<64,EPI_BIAS,false,false><<<dim3(8,64,1),blk,0,stream>>>(
      ffbbf,lin2T,lin2b,nullptr,nullptr,nullptr,ob,nullptr,NT,Dc,FFc,0,0,0);

  // ---- final: out = ln(mem2 + ffout) ----
  ln_sum_kernel<<<dim3(NT),blk,0,stream>>>(big1, ob, n3g, n3b, out);
}

// Round 9
// 657.178 us; speedup vs baseline: 1.0413x; 1.0413x over previous
//
#include <hip/hip_runtime.h>
#include <hip/hip_bf16.h>
#include <math.h>

constexpr int Bc = 2, Lc = 2048, Dc = 1024, Hc = 16, HDc = 64, FFc = 4096;
constexpr int NT = Bc * Lc;              // 4096 tokens
constexpr size_t TD = (size_t)NT * Dc;   // 4194304 elements per [B,L,D] tensor
constexpr size_t MEG = 1024 * 1024;

__device__ __forceinline__ float ldf(const float* p) { return *p; }
__device__ __forceinline__ unsigned short f2b(float f) {
  __hip_bfloat16 h = __float2bfloat16(f);
  return *reinterpret_cast<unsigned short*>(&h);
}

using frag   = __attribute__((ext_vector_type(8))) short;   // 8 bf16 (4 VGPRs)
using f32x4v = __attribute__((ext_vector_type(4))) float;   // MFMA C/D

// async global -> LDS, 16B per lane; LDS dest = wave-uniform base + lane*16
__device__ __forceinline__ void async16(const unsigned short* g, unsigned short* l) {
  __builtin_amdgcn_global_load_lds(
      (const __attribute__((address_space(1))) unsigned int*)g,
      (__attribute__((address_space(3))) unsigned int*)l, 16, 0, 0);
}

// ---------- block reductions (blockDim.x == 256 = 4 waves) ----------
__device__ __forceinline__ float block_sum(float v, float* red) {
  const int lane = threadIdx.x & 63, w = threadIdx.x >> 6;
  #pragma unroll
  for (int o = 32; o > 0; o >>= 1) v += __shfl_down(v, o, 64);
  __syncthreads();
  if (lane == 0) red[w] = v;
  __syncthreads();
  return red[0] + red[1] + red[2] + red[3];
}

// ---------- fp32 -> bf16 convert ----------
__global__ __launch_bounds__(256)
void convert_bf16_kernel(const float* __restrict__ IN, unsigned short* __restrict__ OUT)
{
  const size_t gid = (size_t)blockIdx.x * 256 + threadIdx.x;
  const float4 v = *(const float4*)(IN + gid * 4);
  ushort4 o;
  o.x = f2b(v.x); o.y = f2b(v.y); o.z = f2b(v.z); o.w = f2b(v.w);
  *(ushort4*)(OUT + gid * 4) = o;
}

// ---------- fp32 [R,C] -> bf16 [C,R] transpose-convert (z-batched) ----------
__global__ __launch_bounds__(256)
void transpose_convert_kernel(const float* __restrict__ IN, unsigned short* __restrict__ OUT,
                              int R, int C, long long sIn, long long sOut)
{
  __shared__ float tile[64][65];
  const int t = threadIdx.x;
  const float* in = IN + (long long)blockIdx.z * sIn;
  unsigned short* out = OUT + (long long)blockIdx.z * sOut;
  const int r0 = blockIdx.y * 64, c0 = blockIdx.x * 64;
  #pragma unroll
  for (int i = 0; i < 4; i++) {
    const int r = (t >> 4) + i * 16, c4 = (t & 15) * 4;
    const float4 v = *(const float4*)(in + (size_t)(r0 + r) * C + c0 + c4);
    tile[r][c4+0] = v.x; tile[r][c4+1] = v.y; tile[r][c4+2] = v.z; tile[r][c4+3] = v.w;
  }
  __syncthreads();
  #pragma unroll
  for (int i = 0; i < 4; i++) {
    const int cc = (t >> 4) + i * 16, rr4 = (t & 15) * 4;
    ushort4 o;
    o.x = f2b(tile[rr4+0][cc]); o.y = f2b(tile[rr4+1][cc]);
    o.z = f2b(tile[rr4+2][cc]); o.w = f2b(tile[rr4+3][cc]);
    *(ushort4*)(out + (size_t)(c0 + cc) * R + r0 + rr4) = o;
  }
}

// ---------- fused weight transposes: 10 segments in one launch ----------
struct TPack {
  const float* in[10]; unsigned short* out[10];
  int R[10], C[10], tx[10], start[10];
};
__global__ __launch_bounds__(256)
void fused_transpose_kernel(TPack p)
{
  __shared__ float tile[64][65];
  const int bid = blockIdx.x;
  int s = 0;
  #pragma unroll
  for (int i = 1; i < 10; i++) s = (bid >= p.start[i]) ? i : s;
  const float* in = p.in[s];
  unsigned short* out = p.out[s];
  const int R = p.R[s], C = p.C[s];
  const int local = bid - p.start[s];
  const int bx = local % p.tx[s], by = local / p.tx[s];
  const int r0 = by * 64, c0 = bx * 64;
  const int t = threadIdx.x;
  #pragma unroll
  for (int i = 0; i < 4; i++) {
    const int r = (t >> 4) + i * 16, c4 = (t & 15) * 4;
    const float4 v = *(const float4*)(in + (size_t)(r0 + r) * C + c0 + c4);
    tile[r][c4+0] = v.x; tile[r][c4+1] = v.y; tile[r][c4+2] = v.z; tile[r][c4+3] = v.w;
  }
  __syncthreads();
  #pragma unroll
  for (int i = 0; i < 4; i++) {
    const int cc = (t >> 4) + i * 16, rr4 = (t & 15) * 4;
    ushort4 o;
    o.x = f2b(tile[rr4+0][cc]); o.y = f2b(tile[rr4+1][cc]);
    o.z = f2b(tile[rr4+2][cc]); o.w = f2b(tile[rr4+3][cc]);
    *(ushort4*)(out + (size_t)(c0 + cc) * R + r0 + rr4) = o;
  }
}

// ---------- MFMA bf16 GEMM, double-buffered global_load_lds staging ----------
// C[m,n] = sum_k A[m,k] * Bt[n,k]. Tile BM x 128, BK=32, 2-phase pipeline.
constexpr int EPI_BIAS = 0, EPI_BIAS_ROW = 1, EPI_GELU = 2, EPI_ADD = 3, EPI_ADDROW0 = 4,
              EPI_QKV = 5;

template<int BM, int EPI, bool OUTBF, bool OUTBOTH>
__global__ __launch_bounds__(256)
void mfma_gemm_kernel(const unsigned short* __restrict__ A, const unsigned short* __restrict__ Bt,
                      const float* __restrict__ bias, const float* __restrict__ bias2,
                      const float* __restrict__ bias3, const float* __restrict__ extra,
                      float* __restrict__ C, unsigned short* __restrict__ Cbf,
                      int M, int N, int K,
                      long long sA, long long sB, long long sC)
{
  constexpr int NTt = (BM == 128) ? 4 : 2;   // 16-wide n-fragments per wave
  __shared__ unsigned short As[2][BM][4][8];
  __shared__ unsigned short Bs[2][128][4][8];
  const int tid = threadIdx.x;
  const int l = tid & 63, w = tid >> 6;
  const int wm = (BM == 128) ? (w & 1) * 64 : 0;
  const int wn = (BM == 128) ? (w >> 1) * 64 : w * 32;
  const int m0 = blockIdx.y * BM, n0 = blockIdx.x * 128;
  const unsigned short* Ap = A + (long long)blockIdx.z * sA;
  const unsigned short* Bp = Bt + (long long)blockIdx.z * sB;

  f32x4v acc[4][NTt];
  #pragma unroll
  for (int mt = 0; mt < 4; mt++)
    #pragma unroll
    for (int nt = 0; nt < NTt; nt++) acc[mt][nt] = {0.f, 0.f, 0.f, 0.f};

  const int c_ = l >> 4, rm = l & 15;
  int rrB[2], ggB[2];
  #pragma unroll
  for (int j = 0; j < 2; j++) {
    const int chunk = w * 128 + j * 64 + l;
    rrB[j] = chunk >> 2;
    ggB[j] = (chunk & 3) ^ ((rrB[j] >> 1) & 3);
  }
  int rrA = 0, ggA = 0;
  if constexpr (BM == 64) {
    const int chunkA = w * 64 + l;
    rrA = chunkA >> 2;
    ggA = (chunkA & 3) ^ ((rrA >> 1) & 3);
  }

  auto stage = [&](int bi, int k0) {
    if constexpr (BM == 128) {
      #pragma unroll
      for (int j = 0; j < 2; j++) {
        async16(Ap + (size_t)(m0 + rrB[j]) * K + k0 + ggB[j] * 8,
                &As[bi][0][0][0] + (size_t)(w * 128 + j * 64) * 8);
        async16(Bp + (size_t)(n0 + rrB[j]) * K + k0 + ggB[j] * 8,
                &Bs[bi][0][0][0] + (size_t)(w * 128 + j * 64) * 8);
      }
    } else {
      async16(Ap + (size_t)(m0 + rrA) * K + k0 + ggA * 8,
              &As[bi][0][0][0] + (size_t)(w * 64) * 8);
      #pragma unroll
      for (int j = 0; j < 2; j++)
        async16(Bp + (size_t)(n0 + rrB[j]) * K + k0 + ggB[j] * 8,
                &Bs[bi][0][0][0] + (size_t)(w * 128 + j * 64) * 8);
    }
  };

  stage(0, 0);
  __syncthreads();          // vmcnt(0) drain + barrier
  int cur = 0;
  const int sg = (rm >> 1) & 3;

  for (int k0 = 0; k0 < K; k0 += 32) {
    if (k0 + 32 < K) stage(cur ^ 1, k0 + 32);   // prefetch next tile (other buffer)

    frag af[4], bfr[NTt];
    #pragma unroll
    for (int mt = 0; mt < 4; mt++)
      af[mt] = *(const frag*)&As[cur][wm + mt * 16 + rm][c_ ^ sg][0];
    #pragma unroll
    for (int nt = 0; nt < NTt; nt++)
      bfr[nt] = *(const frag*)&Bs[cur][wn + nt * 16 + rm][c_ ^ sg][0];
    #pragma unroll
    for (int mt = 0; mt < 4; mt++)
      #pragma unroll
      for (int nt = 0; nt < NTt; nt++)
        acc[mt][nt] = __builtin_amdgcn_mfma_f32_16x16x32_bf16(af[mt], bfr[nt], acc[mt][nt], 0, 0, 0);

    __syncthreads();        // drains this iter's lgkm reads + next-tile vmcnt
    cur ^= 1;
  }

  float* Cp = C + (long long)blockIdx.z * sC;
  unsigned short* Cbp = Cbf + (long long)blockIdx.z * sC;
  #pragma unroll
  for (int mt = 0; mt < 4; mt++) {
    #pragma unroll
    for (int nt = 0; nt < NTt; nt++) {
      const int mq = m0 + wm + mt * 16 + c_ * 4;   // quad-base row (i = 0..3 below)
      const int n  = n0 + wn + nt * 16 + rm;       // C/D: col=lane&15
      if constexpr (EPI == EPI_QKV) {
        // n in [0,1024): q (fp32) | [1024,2048): k (fp32) | [2048,3072): V^T bf16
        const float* bp = (n < 1024) ? bias : ((n < 2048) ? bias2 : bias3);
        const float bv_ = ldf(bp + (n & 1023));
        const float r0 = acc[mt][nt][0] + bv_;
        const float r1 = acc[mt][nt][1] + bv_;
        const float r2 = acc[mt][nt][2] + bv_;
        const float r3 = acc[mt][nt][3] + bv_;
        if (n < 2048) {
          float* dst = Cp + (size_t)(n >> 10) * TD + (size_t)mq * Dc + (n & 1023);
          dst[0] = r0; dst[Dc] = r1; dst[2 * Dc] = r2; dst[3 * Dc] = r3;
        } else {
          ushort4 o;
          o.x = f2b(r0); o.y = f2b(r1); o.z = f2b(r2); o.w = f2b(r3);
          *(ushort4*)(Cbp + (size_t)(mq >> 11) * ((size_t)Lc * Dc)
                      + (size_t)(n - 2048) * Lc + (mq & (Lc - 1))) = o;
        }
      } else {
        #pragma unroll
        for (int i = 0; i < 4; i++) {
          const int m = mq + i;                     // C/D: row=(lane>>4)*4+reg
          float r = acc[mt][nt][i];
          if constexpr (EPI == EPI_BIAS || EPI == EPI_GELU || EPI == EPI_ADD || EPI == EPI_ADDROW0)
            r += ldf(bias + n);
          if constexpr (EPI == EPI_BIAS_ROW) r += ldf(bias + m);
          if constexpr (EPI == EPI_GELU)
            r = 0.5f * r * (1.0f + erff(r * 0.70710678118654752f));
          if constexpr (EPI == EPI_ADD) r += extra[(size_t)m * N + n];
          if constexpr (EPI == EPI_ADDROW0) r += extra[(size_t)(m >> 11) * ((size_t)Lc * Dc) + n];
          if constexpr (OUTBOTH) { Cp[(size_t)m * N + n] = r; Cbp[(size_t)m * N + n] = f2b(r); }
          else if constexpr (OUTBF) Cbp[(size_t)m * N + n] = f2b(r);
          else                      Cp[(size_t)m * N + n] = r;
        }
      }
    }
  }
}

// ---------- RoPE table fill ----------
__global__ __launch_bounds__(256)
void pe_fill_kernel(float* __restrict__ pet)
{
  const int gid = blockIdx.x * 256 + threadIdx.x;  // Lc*64
  const int l = gid >> 6, t = gid & 63;
  const int j = t & 31;
  const float wj = exp2f(-(float)j * (13.2877123795494f / 32.0f));
  const float ang = (float)l * wj;
  pet[gid] = (t < 32) ? cosf(ang) : sinf(ang);
}

// ---------- fused RoPE for Q and K: fp32 in, bf16 out ----------
// Q is pre-scaled by 0.125*log2(e) so flash-attn softmax works in base-2
// with zero per-element scale ops.
__global__ __launch_bounds__(256)
void rope2_kernel(const float* __restrict__ Qi, const float* __restrict__ Ki,
                  const float* __restrict__ pet,
                  unsigned short* __restrict__ Qo, unsigned short* __restrict__ Ko)
{
  int gid = blockIdx.x * 256 + threadIdx.x;  // 2*NT*Hc
  const int sel = gid >= NT * Hc;            // block-uniform (NT*Hc % 256 == 0)
  if (sel) gid -= NT * Hc;
  const float* X = sel ? Ki : Qi;
  unsigned short* O = sel ? Ko : Qo;
  const float scl = sel ? 1.0f : 0.125f * 1.44269504f;
  const int h = gid & (Hc - 1);
  const int token = gid >> 4;
  const int l = token & (Lc - 1);
  const float* p = X + (size_t)token * Dc + h * HDc;
  unsigned short* po = O + (size_t)token * Dc + h * HDc;
  const float* pr = pet + l * 64;
  float x[64], out[64];
  #pragma unroll
  for (int i = 0; i < 16; i++) *(float4*)&x[4*i] = *(const float4*)&p[4*i];
  #pragma unroll
  for (int u = 0; u < 32; u++) {
    const int base = (u < 16) ? (2 * u) : (32 + 2 * (u - 16));
    const float c = pr[base], s = pr[base + 1];
    out[u]      = (x[2*u] * c - x[2*u+1] * s) * scl;
    out[32 + u] = (x[2*u] * s + x[2*u+1] * c) * scl;
  }
  #pragma unroll
  for (int i = 0; i < 16; i++) {
    ushort4 o;
    o.x = f2b(out[4*i+0]); o.y = f2b(out[4*i+1]);
    o.z = f2b(out[4*i+2]); o.w = f2b(out[4*i+3]);
    *(ushort4*)&po[4*i] = o;
  }
}

// ---------- per-tile max row-norm of Q (scaled) and K, from the bf16 data ----------
__global__ __launch_bounds__(256)
void tile_norm_kernel(const unsigned short* __restrict__ Qb,
                      const unsigned short* __restrict__ Kb,
                      float* __restrict__ qnb, float* __restrict__ knb)
{
  __shared__ float red[4];
  const int tile = blockIdx.x, bh = blockIdx.y;
  const int b = bh >> 4, h = bh & 15;
  const unsigned short* X = blockIdx.z ? Qb : Kb;
  const int tid = threadIdx.x;
  const int row = tid >> 2, seg = tid & 3;
  const unsigned short* p = X + ((size_t)(b * Lc + tile * 64 + row)) * Dc + h * 64 + seg * 16;
  const uint4 v0 = *(const uint4*)p;
  const uint4 v1 = *(const uint4*)(p + 8);
  const unsigned int vv[8] = {v0.x, v0.y, v0.z, v0.w, v1.x, v1.y, v1.z, v1.w};
  float ss = 0.f;
  #pragma unroll
  for (int i = 0; i < 8; i++) {
    const float a = __uint_as_float(vv[i] << 16);
    const float c = __uint_as_float(vv[i] & 0xffff0000u);
    ss = fmaf(a, a, ss); ss = fmaf(c, c, ss);
  }
  ss += __shfl_xor(ss, 1, 64);
  ss += __shfl_xor(ss, 2, 64);          // all 4 lanes of a row-group: full row sumsq
  float mx = ss;
  mx = fmaxf(mx, __shfl_xor(mx, 4, 64));
  mx = fmaxf(mx, __shfl_xor(mx, 8, 64));
  mx = fmaxf(mx, __shfl_xor(mx, 16, 64));
  mx = fmaxf(mx, __shfl_xor(mx, 32, 64));
  if ((tid & 63) == 0) red[tid >> 6] = mx;
  __syncthreads();
  if (tid == 0) {
    const float r = fmaxf(fmaxf(red[0], red[1]), fmaxf(red[2], red[3]));
    (blockIdx.z ? qnb : knb)[bh * 32 + tile] = sqrtf(r);
  }
}

// ---------- MFMA flash attention v9 ----------
// v8 body (bound-skip + runtime-skip + dbuf) with ONE change: heavy-first,
// spread block ordering. ALiBi bias = +slope*dist makes per-head work
// ~18.7*2^(h/2) tokens; the old (q0, bh) grid clustered the no-skip h=14/15
// blocks 2-deep on CUs 224..255 AND dispatched them last -> they were the
// wall. 1-D grid: h = 15 - bid/64 (heaviest heads first, spread over 64
// CUs each), rem -> (b, q0).
__global__ __launch_bounds__(256)
void flash_attn_mfma_kernel(const unsigned short* __restrict__ Q,
                            const unsigned short* __restrict__ K,
                            const unsigned short* __restrict__ VT,
                            const float* __restrict__ qnb,
                            const float* __restrict__ knb,
                            unsigned short* __restrict__ O)
{
  __shared__ unsigned short Qs[64][8][8];
  __shared__ unsigned short Ks[2][64][8][8];
  __shared__ unsigned short Vt[2][64][8][8];
  __shared__ unsigned short Ps[64][72];
  __shared__ float knS[32];
  __shared__ float mS[64];
  const int tid = threadIdx.x;
  const int l = tid & 63, w = tid >> 6;
  const int lg = l >> 4, lm = l & 15;
  // heavy-first decode: h descends with bid/64; (b,q0) spread within
  const int bid = blockIdx.x;
  const int h = 15 - (bid >> 6);
  const int rem = bid & 63;
  const int b = rem & 1;
  const int qi = rem >> 1;
  const int q0 = qi * 64;
  const int bh = b * 16 + h;
  const size_t rowbase = (size_t)b * Lc;
  const size_t vbase = (size_t)b * Lc * Dc;
  const int dbase = h * 64;
  const float sl2 = exp2f(-0.5f * (float)h) * 1.44269504f; // slope * log2(e)

  auto stageKV = [&](int bi, int k0s) {
    #pragma unroll
    for (int j = 0; j < 2; j++) {
      const int chunk = (w * 2 + j) * 64 + l;
      const int r = chunk >> 3, gsrc = (chunk & 7) ^ (r & 7);
      async16(K + (rowbase + k0s + r) * Dc + dbase + gsrc * 8,
              &Ks[bi][0][0][0] + (size_t)chunk * 8);
      async16(VT + vbase + (size_t)(dbase + r) * Lc + k0s + gsrc * 8,
              &Vt[bi][0][0][0] + (size_t)chunk * 8);
    }
  };

  // ---- stage Q + first K/V tile; load norms ----
  #pragma unroll
  for (int j = 0; j < 2; j++) {
    const int chunk = (w * 2 + j) * 64 + l;
    const int r = chunk >> 3, gsrc = (chunk & 7) ^ (r & 7);
    async16(Q + (rowbase + q0 + r) * Dc + dbase + gsrc * 8,
            &Qs[0][0][0] + (size_t)chunk * 8);
  }
  stageKV(0, 0);
  const float qmx = qnb[bh * 32 + qi] * 1.01f;  // slack for fp32 norm rounding
  if (tid < 32) knS[tid] = knb[bh * 32 + tid];
  if (tid < 64) mS[tid] = -3.0e38f;
  __syncthreads();
  frag qf[2];
  #pragma unroll
  for (int s = 0; s < 2; s++)
    qf[s] = *(const frag*)&Qs[w * 16 + lm][(s * 4 + lg) ^ (lm & 7)][0];

  // per-lane constants
  const float qg = (float)(q0 + w * 16 + lm);
  float koff[4][4];
  #pragma unroll
  for (int kt = 0; kt < 4; kt++)
    #pragma unroll
    for (int i = 0; i < 4; i++) koff[kt][i] = (float)(kt * 16 + lg * 4 + i);

  float m_i = -3.0e38f, l_i = 0.f;
  f32x4v acc_o[4];
  #pragma unroll
  for (int dt = 0; dt < 4; dt++) acc_o[dt] = {0.f, 0.f, 0.f, 0.f};

  int nslot = 1;                         // slot for the next staged tile
  bool staged_cur = true; int slot_cur = 0;   // tile 0 staged in slot 0
  bool staged_next = false; int slot_next = 0;

  for (int t = 0; t < Lc / 64; ++t) {
    const int k0 = t * 64;

    // ---- block-uniform running min of m over all 64 rows ----
    float mb = mS[l];
    mb = fminf(mb, __shfl_xor(mb, 1, 64));
    mb = fminf(mb, __shfl_xor(mb, 2, 64));
    mb = fminf(mb, __shfl_xor(mb, 4, 64));
    mb = fminf(mb, __shfl_xor(mb, 8, 64));
    mb = fminf(mb, __shfl_xor(mb, 16, 64));
    mb = fminf(mb, __shfl_xor(mb, 32, 64));

    // ---- bound-skip decision + conditional staging of tile t+1 ----
    if (t + 1 < Lc / 64) {
      const int u = t + 1;
      const float biasmax = sl2 * fmaxf((float)(q0 + 63 - 64 * u), 0.f);
      staged_next = (qmx * knS[u] + biasmax) >= mb - 27.0f;
      if (staged_next) { slot_next = nslot; stageKV(nslot, u * 64); nslot ^= 1; }
    } else staged_next = false;

    if (staged_cur) {
      // ---- S^T = K Q^T : rows k (64), cols q (16 of this wave) ----
      f32x4v st[4];
      #pragma unroll
      for (int kt = 0; kt < 4; kt++) st[kt] = {0.f, 0.f, 0.f, 0.f};
      __builtin_amdgcn_s_setprio(1);
      #pragma unroll
      for (int kt = 0; kt < 4; kt++) {
        #pragma unroll
        for (int s = 0; s < 2; s++) {
          frag kf = *(const frag*)&Ks[slot_cur][kt * 16 + lm][(s * 4 + lg) ^ (lm & 7)][0];
          st[kt] = __builtin_amdgcn_mfma_f32_16x16x32_bf16(kf, qf[s], st[kt], 0, 0, 0);
        }
      }
      __builtin_amdgcn_s_setprio(0);

      // ---- bias by region (block-uniform branch) + row max ----
      const float qk0 = qg - (float)k0;
      float sv[4][4], tmax = -3.0e38f;
      if (k0 + 64 <= q0) {           // fully past: bias = sl2*(qg-kg), linear
        #pragma unroll
        for (int kt = 0; kt < 4; kt++)
          #pragma unroll
          for (int i = 0; i < 4; i++) {
            const float v = fmaf(sl2, qk0 - koff[kt][i], st[kt][i]);
            sv[kt][i] = v; tmax = fmaxf(tmax, v);
          }
      } else if (k0 <= q0) {         // diagonal tile: clamp at 0
        #pragma unroll
        for (int kt = 0; kt < 4; kt++)
          #pragma unroll
          for (int i = 0; i < 4; i++) {
            const float v = fmaf(sl2, fmaxf(qk0 - koff[kt][i], 0.f), st[kt][i]);
            sv[kt][i] = v; tmax = fmaxf(tmax, v);
          }
      } else {                       // fully future: bias = 0
        #pragma unroll
        for (int kt = 0; kt < 4; kt++)
          #pragma unroll
          for (int i = 0; i < 4; i++) {
            const float v = st[kt][i];
            sv[kt][i] = v; tmax = fmaxf(tmax, v);
          }
      }
      tmax = fmaxf(tmax, __shfl_xor(tmax, 16, 64));
      tmax = fmaxf(tmax, __shfl_xor(tmax, 32, 64));

      // ---- runtime tile skip (second layer) ----
      if (!__all(tmax < m_i - 27.0f)) {
        if (__any(tmax > m_i)) {     // exact skip: otherwise alpha == 1
          const float mnew = fmaxf(m_i, tmax);
          const float alpha = exp2f(m_i - mnew);
          m_i = mnew;
          l_i *= alpha;
          float aO[4];
          #pragma unroll
          for (int i = 0; i < 4; i++) aO[i] = __shfl(alpha, lg * 4 + i, 64);
          #pragma unroll
          for (int dt = 0; dt < 4; dt++)
            #pragma unroll
            for (int i = 0; i < 4; i++) acc_o[dt][i] *= aO[i];
        }
        float rsum = 0.f;
        const int qrow = w * 16 + lm;
        #pragma unroll
        for (int kt = 0; kt < 4; kt++) {
          const float p0 = exp2f(sv[kt][0] - m_i), p1 = exp2f(sv[kt][1] - m_i);
          const float p2 = exp2f(sv[kt][2] - m_i), p3 = exp2f(sv[kt][3] - m_i);
          rsum += (p0 + p1) + (p2 + p3);
          unsigned int w0, w1;       // packed bf16 pairs (lo=first arg)
          asm("v_cvt_pk_bf16_f32 %0, %1, %2" : "=v"(w0) : "v"(p0), "v"(p1));
          asm("v_cvt_pk_bf16_f32 %0, %1, %2" : "=v"(w1) : "v"(p2), "v"(p3));
          uint2 pw; pw.x = w0; pw.y = w1;
          *(uint2*)&Ps[qrow][kt * 16 + lg * 4] = pw;   // 4 consecutive k
        }
        rsum += __shfl_xor(rsum, 16, 64);
        rsum += __shfl_xor(rsum, 32, 64);
        l_i += rsum;

        // ---- O += P V (Ps rows wave-private) ----
        __builtin_amdgcn_s_setprio(1);
        #pragma unroll
        for (int c = 0; c < 2; c++) {
          frag ap = *(const frag*)&Ps[w * 16 + lm][c * 32 + lg * 8];
          #pragma unroll
          for (int dt = 0; dt < 4; dt++) {
            frag bv = *(const frag*)&Vt[slot_cur][dt * 16 + lm][(c * 4 + lg) ^ (lm & 7)][0];
            acc_o[dt] = __builtin_amdgcn_mfma_f32_16x16x32_bf16(ap, bv, acc_o[dt], 0, 0, 0);
          }
        }
        __builtin_amdgcn_s_setprio(0);
      }
      if (lg == 0) mS[w * 16 + lm] = m_i;   // publish running max for block-min
    }

    __syncthreads();    // drains staged loads + this iter's LDS reads
    staged_cur = staged_next; slot_cur = slot_next;
  }

  // ---- epilogue: normalize, bounce through Ps, coalesced store ----
  float lO[4];
  #pragma unroll
  for (int i = 0; i < 4; i++) lO[i] = 1.0f / __shfl(l_i, lg * 4 + i, 64);
  #pragma unroll
  for (int dt = 0; dt < 4; dt++)
    #pragma unroll
    for (int i = 0; i < 4; i++)
      Ps[w * 16 + lg * 4 + i][dt * 16 + lm] = f2b(acc_o[dt][i] * lO[i]);
  __syncthreads();
  #pragma unroll
  for (int j = 0; j < 2; j++) {
    const int chunk = (w * 2 + j) * 64 + l;
    const int r = chunk >> 3, g = chunk & 7;
    alignas(16) unsigned short tmp[8];
    #pragma unroll
    for (int t = 0; t < 8; t++) tmp[t] = Ps[r][g * 8 + t];
    *(uint4*)(O + (rowbase + q0 + r) * Dc + dbase + g * 8) = *(uint4*)tmp;
  }
}

// ---------- fused: mem1 = RES + ln(X;n1) -> fp32; hln = ln(mem1;cln) -> bf16 ----
__global__ __launch_bounds__(256)
void ln_res_cln_kernel(const float* __restrict__ X, const float* __restrict__ RES,
                       const float* __restrict__ g1, const float* __restrict__ b1,
                       const float* __restrict__ g2, const float* __restrict__ b2,
                       float* __restrict__ OUT1, unsigned short* __restrict__ OUT2)
{
  __shared__ float red4[4];
  const int row = blockIdx.x, tid = threadIdx.x;
  const size_t base = (size_t)row * Dc + tid * 4;
  const float4 xv = *(const float4*)(X + base);
  float s = xv.x + xv.y + xv.z + xv.w;
  s = block_sum(s, red4);
  const float mean = s * (1.0f / Dc);
  const float d0 = xv.x-mean, d1 = xv.y-mean, d2 = xv.z-mean, d3 = xv.w-mean;
  float ss = d0*d0 + d1*d1 + d2*d2 + d3*d3;
  ss = block_sum(ss, red4);
  const float rstd = rsqrtf(ss * (1.0f / Dc) + 1e-5f);
  const int c = tid * 4;
  const float4 rv = *(const float4*)(RES + base);
  float y0 = rv.x + d0*rstd*ldf(g1+c+0) + ldf(b1+c+0);
  float y1 = rv.y + d1*rstd*ldf(g1+c+1) + ldf(b1+c+1);
  float y2 = rv.z + d2*rstd*ldf(g1+c+2) + ldf(b1+c+2);
  float y3 = rv.w + d3*rstd*ldf(g1+c+3) + ldf(b1+c+3);
  *(float4*)(OUT1 + base) = make_float4(y0, y1, y2, y3);
  float s2 = y0 + y1 + y2 + y3;
  s2 = block_sum(s2, red4);
  const float mean2 = s2 * (1.0f / Dc);
  const float e0 = y0-mean2, e1 = y1-mean2, e2 = y2-mean2, e3 = y3-mean2;
  float ss2 = e0*e0 + e1*e1 + e2*e2 + e3*e3;
  ss2 = block_sum(ss2, red4);
  const float rstd2 = rsqrtf(ss2 * (1.0f / Dc) + 1e-5f);
  ushort4 o;
  o.x = f2b(e0*rstd2*ldf(g2+c+0) + ldf(b2+c+0));
  o.y = f2b(e1*rstd2*ldf(g2+c+1) + ldf(b2+c+1));
  o.z = f2b(e2*rstd2*ldf(g2+c+2) + ldf(b2+c+2));
  o.w = f2b(e3*rstd2*ldf(g2+c+3) + ldf(b2+c+3));
  *(ushort4*)(OUT2 + base) = o;
}

__global__ __launch_bounds__(256)   // OUT = ln(X + Y)
void ln_sum_kernel(const float* __restrict__ X, const float* __restrict__ Y,
                   const float* __restrict__ g, const float* __restrict__ be,
                   float* __restrict__ OUT)
{
  __shared__ float red4[4];
  const int row = blockIdx.x, tid = threadIdx.x;
  const size_t base = (size_t)row * Dc + tid * 4;
  const float4 xv = *(const float4*)(X + base);
  const float4 yv = *(const float4*)(Y + base);
  const float x0 = xv.x+yv.x, x1 = xv.y+yv.y, x2 = xv.z+yv.z, x3 = xv.w+yv.w;
  float s = x0 + x1 + x2 + x3;
  s = block_sum(s, red4);
  const float mean = s * (1.0f / Dc);
  const float d0 = x0-mean, d1 = x1-mean, d2 = x2-mean, d3 = x3-mean;
  float ss = d0*d0 + d1*d1 + d2*d2 + d3*d3;
  ss = block_sum(ss, red4);
  const float rstd = rsqrtf(ss * (1.0f / Dc) + 1e-5f);
  const int c = tid * 4;
  float4 o;
  o.x = d0*rstd*ldf(g+c+0) + ldf(be+c+0);
  o.y = d1*rstd*ldf(g+c+1) + ldf(be+c+1);
  o.z = d2*rstd*ldf(g+c+2) + ldf(be+c+2);
  o.w = d3*rstd*ldf(g+c+3) + ldf(be+c+3);
  *(float4*)(OUT + base) = o;
}

// ---------- GLU ----------
__global__ __launch_bounds__(256)
void glu_kernel(const float* __restrict__ H1, float* __restrict__ HG)
{
  const int gid = blockIdx.x * 256 + threadIdx.x;
  const int t = gid >> 8;
  const int c4 = (gid & 255) * 4;
  const float* p = H1 + (size_t)t * (2 * Dc);
  const float4 a = *(const float4*)(p + c4);
  const float4 gg = *(const float4*)(p + Dc + c4);
  float4 o;
  o.x = a.x / (1.0f + expf(-gg.x));
  o.y = a.y / (1.0f + expf(-gg.y));
  o.z = a.z / (1.0f + expf(-gg.z));
  o.w = a.w / (1.0f + expf(-gg.w));
  *(float4*)(HG + (size_t)t * Dc + c4) = o;
}

// ---------- depthwise conv K=5 (+bias, bn-scale, hardswish), bf16 out ----------
__global__ __launch_bounds__(256)
void dwconv_bf16_kernel(const float* __restrict__ HG, const float* __restrict__ w,
                        const float* __restrict__ wb, const float* __restrict__ gn,
                        const float* __restrict__ bb, unsigned short* __restrict__ OUT)
{
  const int gid = blockIdx.x * 256 + threadIdx.x;
  const int d = gid & (Dc - 1);
  const int l = (gid >> 10) & (Lc - 1);
  const int b = gid >> 21;
  const size_t rowb = (size_t)b * Lc;
  float acc = ldf(wb + d);
  #pragma unroll
  for (int s = 0; s < 5; s++) {
    const int lp = l + 2 - s;
    if (lp >= 0 && lp < Lc)
      acc += ldf(w + d * 5 + s) * HG[((rowb + lp) << 10) + d];
  }
  const float rs = rsqrtf(1.0f + 1e-5f);
  const float t = acc * rs * ldf(gn + d) + ldf(bb + d);
  OUT[gid] = f2b(t * fminf(fmaxf(t + 3.0f, 0.0f), 6.0f) * (1.0f / 6.0f));
}

// =====================================================================
extern "C" void kernel_launch(void* const* d_in, const int* in_sizes, int n_in,
                              void* d_out, int out_size, void* d_ws, size_t ws_size,
                              hipStream_t stream) {
  (void)in_sizes; (void)n_in; (void)out_size; (void)ws_size;
  const float* mem    = (const float*)d_in[0];
  const float* wq     = (const float*)d_in[1];
  const float* bq     = (const float*)d_in[2];
  const float* wk     = (const float*)d_in[3];
  const float* bk     = (const float*)d_in[4];
  const float* wv     = (const float*)d_in[5];
  const float* bv     = (const float*)d_in[6];
  const float* wo     = (const float*)d_in[7];
  const float* bo     = (const float*)d_in[8];
  const float* n1g    = (const float*)d_in[9];
  const float* n1b    = (const float*)d_in[10];
  const float* clng   = (const float*)d_in[11];
  const float* clnb   = (const float*)d_in[12];
  const float* pw1w   = (const float*)d_in[13];
  const float* pw1b   = (const float*)d_in[14];
  const float* dww    = (const float*)d_in[15];
  const float* dwb    = (const float*)d_in[16];
  const float* bng    = (const float*)d_in[17];
  const float* bnb    = (const float*)d_in[18];
  const float* pw2w   = (const float*)d_in[19];
  const float* pw2b   = (const float*)d_in[20];
  const float* projw  = (const float*)d_in[21];
  const float* projb  = (const float*)d_in[22];
  const float* proj2w = (const float*)d_in[23];
  const float* proj2b = (const float*)d_in[24];
  const float* lin1w  = (const float*)d_in[25];
  const float* lin1b  = (const float*)d_in[26];
  const float* lin2w  = (const float*)d_in[27];
  const float* lin2b  = (const float*)d_in[28];
  const float* n3g    = (const float*)d_in[29];
  const float* n3b    = (const float*)d_in[30];
  float* out = (float*)d_out;

  char* base = (char*)d_ws;
  float* qb   = (float*)base;          // q fp32 -> tgt2 fp32
  float* kb   = qb + TD;               // k fp32 -> mem1
  float* big1 = kb + TD;               // h1 lo -> mem2 fp32
  float* big2 = big1 + TD;             // h1 hi -> conv_out
  float* ob   = big2 + TD;             // hg -> ffout
  unsigned short* abf  = (unsigned short*)(base + 5 * TD * 4);  // bf16 hub
  unsigned short* qbf  = abf + TD;     // rope-q -> mem2 bf16
  unsigned short* kbf  = qbf + TD;
  unsigned short* vtb  = kbf + TD;     // V^T bf16  [b][1024 d][2048 l]
  unsigned short* m1T  = vtb + TD;
  unsigned short* ffbbf= m1T + TD;     // NT*FF = 4*TD shorts
  unsigned short* wt   = ffbbf + 4 * TD;
  unsigned short* wqT    = wt;            // [1024][1024] } contiguous => [3072][1024] fused QKV B^T
  unsigned short* wkT    = wqT + MEG;
  unsigned short* wvT    = wkT + MEG;
  unsigned short* woT    = wvT + MEG;
  unsigned short* pw1T   = woT + MEG;     // [2048][1024]
  unsigned short* pw2T   = pw1T + 2*MEG;  // [1024][1024]
  unsigned short* proj2T = pw2T + MEG;    // [1024][1024]
  unsigned short* projwT = proj2T + MEG;  // [2048][2048]
  unsigned short* lin1T  = projwT + 4*MEG;// [4096][1024]
  unsigned short* lin2T  = lin1T + 4*MEG; // [1024][4096]
  float* pet = (float*)(lin2T + 4*MEG);   // [2048][64] rope table
  float* knb = pet + (size_t)Lc * 64;     // [32 bh][32 tiles] K max row-norm
  float* qnb = knb + 1024;                // [32 bh][32 qblocks] Q max row-norm

  const dim3 blk(256);
  const long long LD = (long long)Lc * Dc;

  // ---- fused weight transposes + rope table ----
  TPack tp;
  const float* tin[10]  = {wq, wk, wv, wo, pw1w, pw2w, proj2w, projw, lin1w, lin2w};
  unsigned short* tout[10] = {wqT, wkT, wvT, woT, pw1T, pw2T, proj2T, projwT, lin1T, lin2T};
  const int tR[10] = {1024,1024,1024,1024,1024,1024,1024,2048,1024,4096};
  const int tC[10] = {1024,1024,1024,1024,2048,1024,1024,2048,4096,1024};
  int startAcc = 0;
  for (int i = 0; i < 10; i++) {
    tp.in[i] = tin[i]; tp.out[i] = tout[i];
    tp.R[i] = tR[i]; tp.C[i] = tC[i]; tp.tx[i] = tC[i] / 64;
    tp.start[i] = startAcc;
    startAcc += (tR[i] / 64) * (tC[i] / 64);
  }
  fused_transpose_kernel<<<dim3(startAcc), blk, 0, stream>>>(tp);
  pe_fill_kernel<<<dim3(Lc * 64 / 256), blk, 0, stream>>>(pet);

  // ---- attention ----
  convert_bf16_kernel<<<dim3((unsigned)(TD/1024)),blk,0,stream>>>(mem, abf);
  // fused QKV: N=3072, q->qb fp32, k->kb fp32, V->vtb transposed bf16 directly
  mfma_gemm_kernel<128,EPI_QKV,false,false><<<dim3(24,32,1),blk,0,stream>>>(
      abf, wqT, bq, bk, bv, nullptr, qb, vtb, NT, 3*Dc, Dc, 0, 0, 0);
  rope2_kernel<<<dim3(2*NT*Hc/256),blk,0,stream>>>(qb, kb, pet, qbf, kbf);
  tile_norm_kernel<<<dim3(32,32,2),blk,0,stream>>>(qbf, kbf, qnb, knb);
  flash_attn_mfma_kernel<<<dim3(1024),blk,0,stream>>>(qbf,kbf,vtb,qnb,knb,abf);
  mfma_gemm_kernel<64,EPI_BIAS,false,false><<<dim3(8,64,1),blk,0,stream>>>(
      abf,woT,bo,nullptr,nullptr,nullptr,qb,nullptr,NT,Dc,Dc,0,0,0);
  // mem1 (fp32 -> kb) and ln(mem1) (bf16 -> abf) in one pass
  ln_res_cln_kernel<<<dim3(NT),blk,0,stream>>>(qb, mem, n1g, n1b, clng, clnb, kb, abf);

  // ---- conv block ----
  mfma_gemm_kernel<128,EPI_BIAS,false,false><<<dim3(16,32,1),blk,0,stream>>>(
      abf,pw1T,pw1b,nullptr,nullptr,nullptr,big1,nullptr,NT,2*Dc,Dc,0,0,0);
  glu_kernel<<<dim3((unsigned)(TD/4/256)),blk,0,stream>>>(big1, ob);
  dwconv_bf16_kernel<<<dim3((unsigned)(TD/256)),blk,0,stream>>>(ob, dww, dwb, bng, bnb, abf);
  mfma_gemm_kernel<64,EPI_ADDROW0,false,false><<<dim3(8,64,1),blk,0,stream>>>(
      abf,pw2T,pw2b,nullptr,nullptr,kb,big2,nullptr,NT,Dc,Dc,0,0,0);

  // ---- proj path ----
  transpose_convert_kernel<<<dim3(16,32,2),blk,0,stream>>>(kb, m1T, 2048, 1024, LD, LD);
  mfma_gemm_kernel<64,EPI_BIAS_ROW,true,false><<<dim3(8,32,2),blk,0,stream>>>(
      projwT,m1T,projb,nullptr,nullptr,nullptr,nullptr,abf,Lc,Dc,Lc,0,LD,LD);
  // mem2 = proj@proj2 + conv_out: fp32 -> big1 AND bf16 -> qbf (feeds lin1)
  mfma_gemm_kernel<64,EPI_ADD,false,true><<<dim3(8,64,1),blk,0,stream>>>(
      abf,proj2T,proj2b,nullptr,nullptr,big2,big1,qbf,NT,Dc,Dc,0,0,0);

  // ---- feed-forward ----
  mfma_gemm_kernel<128,EPI_GELU,true,false><<<dim3(32,32,1),blk,0,stream>>>(
      qbf,lin1T,lin1b,nullptr,nullptr,nullptr,nullptr,ffbbf,NT,FFc,Dc,0,0,0);
  mfma_gemm_kernel<64,EPI_BIAS,false,false><<<dim3(8,64,1),blk,0,stream>>>(
      ffbbf,lin2T,lin2b,nullptr,nullptr,nullptr,ob,nullptr,NT,Dc,FFc,0,0,0);

  // ---- final: out = ln(mem2 + ffout) ----
  ln_sum_kernel<<<dim3(NT),blk,0,stream>>>(big1, ob, n3g, n3b, out);
}

// Round 10
// 637.973 us; speedup vs baseline: 1.0726x; 1.0301x over previous
//
#include <hip/hip_runtime.h>
#include <hip/hip_bf16.h>
#include <math.h>

constexpr int Bc = 2, Lc = 2048, Dc = 1024, Hc = 16, HDc = 64, FFc = 4096;
constexpr int NT = Bc * Lc;              // 4096 tokens
constexpr size_t TD = (size_t)NT * Dc;   // 4194304 elements per [B,L,D] tensor
constexpr size_t MEG = 1024 * 1024;

__device__ __forceinline__ float ldf(const float* p) { return *p; }
__device__ __forceinline__ unsigned short f2b(float f) {
  __hip_bfloat16 h = __float2bfloat16(f);
  return *reinterpret_cast<unsigned short*>(&h);
}

using frag   = __attribute__((ext_vector_type(8))) short;   // 8 bf16 (4 VGPRs)
using f32x4v = __attribute__((ext_vector_type(4))) float;   // MFMA C/D

// async global -> LDS, 16B per lane; LDS dest = wave-uniform base + lane*16
__device__ __forceinline__ void async16(const unsigned short* g, unsigned short* l) {
  __builtin_amdgcn_global_load_lds(
      (const __attribute__((address_space(1))) unsigned int*)g,
      (__attribute__((address_space(3))) unsigned int*)l, 16, 0, 0);
}

// ---------- block reductions (blockDim.x == 256 = 4 waves) ----------
__device__ __forceinline__ float block_sum(float v, float* red) {
  const int lane = threadIdx.x & 63, w = threadIdx.x >> 6;
  #pragma unroll
  for (int o = 32; o > 0; o >>= 1) v += __shfl_down(v, o, 64);
  __syncthreads();
  if (lane == 0) red[w] = v;
  __syncthreads();
  return red[0] + red[1] + red[2] + red[3];
}

// ---------- fp32 -> bf16 convert ----------
__global__ __launch_bounds__(256)
void convert_bf16_kernel(const float* __restrict__ IN, unsigned short* __restrict__ OUT)
{
  const size_t gid = (size_t)blockIdx.x * 256 + threadIdx.x;
  const float4 v = *(const float4*)(IN + gid * 4);
  ushort4 o;
  o.x = f2b(v.x); o.y = f2b(v.y); o.z = f2b(v.z); o.w = f2b(v.w);
  *(ushort4*)(OUT + gid * 4) = o;
}

// ---------- fp32 [R,C] -> bf16 [C,R] transpose-convert (z-batched) ----------
__global__ __launch_bounds__(256)
void transpose_convert_kernel(const float* __restrict__ IN, unsigned short* __restrict__ OUT,
                              int R, int C, long long sIn, long long sOut)
{
  __shared__ float tile[64][65];
  const int t = threadIdx.x;
  const float* in = IN + (long long)blockIdx.z * sIn;
  unsigned short* out = OUT + (long long)blockIdx.z * sOut;
  const int r0 = blockIdx.y * 64, c0 = blockIdx.x * 64;
  #pragma unroll
  for (int i = 0; i < 4; i++) {
    const int r = (t >> 4) + i * 16, c4 = (t & 15) * 4;
    const float4 v = *(const float4*)(in + (size_t)(r0 + r) * C + c0 + c4);
    tile[r][c4+0] = v.x; tile[r][c4+1] = v.y; tile[r][c4+2] = v.z; tile[r][c4+3] = v.w;
  }
  __syncthreads();
  #pragma unroll
  for (int i = 0; i < 4; i++) {
    const int cc = (t >> 4) + i * 16, rr4 = (t & 15) * 4;
    ushort4 o;
    o.x = f2b(tile[rr4+0][cc]); o.y = f2b(tile[rr4+1][cc]);
    o.z = f2b(tile[rr4+2][cc]); o.w = f2b(tile[rr4+3][cc]);
    *(ushort4*)(out + (size_t)(c0 + cc) * R + r0 + rr4) = o;
  }
}

// ---------- fused weight transposes: 10 segments in one launch ----------
struct TPack {
  const float* in[10]; unsigned short* out[10];
  int R[10], C[10], tx[10], start[10];
};
__global__ __launch_bounds__(256)
void fused_transpose_kernel(TPack p)
{
  __shared__ float tile[64][65];
  const int bid = blockIdx.x;
  int s = 0;
  #pragma unroll
  for (int i = 1; i < 10; i++) s = (bid >= p.start[i]) ? i : s;
  const float* in = p.in[s];
  unsigned short* out = p.out[s];
  const int R = p.R[s], C = p.C[s];
  const int local = bid - p.start[s];
  const int bx = local % p.tx[s], by = local / p.tx[s];
  const int r0 = by * 64, c0 = bx * 64;
  const int t = threadIdx.x;
  #pragma unroll
  for (int i = 0; i < 4; i++) {
    const int r = (t >> 4) + i * 16, c4 = (t & 15) * 4;
    const float4 v = *(const float4*)(in + (size_t)(r0 + r) * C + c0 + c4);
    tile[r][c4+0] = v.x; tile[r][c4+1] = v.y; tile[r][c4+2] = v.z; tile[r][c4+3] = v.w;
  }
  __syncthreads();
  #pragma unroll
  for (int i = 0; i < 4; i++) {
    const int cc = (t >> 4) + i * 16, rr4 = (t & 15) * 4;
    ushort4 o;
    o.x = f2b(tile[rr4+0][cc]); o.y = f2b(tile[rr4+1][cc]);
    o.z = f2b(tile[rr4+2][cc]); o.w = f2b(tile[rr4+3][cc]);
    *(ushort4*)(out + (size_t)(c0 + cc) * R + r0 + rr4) = o;
  }
}

// ---------- MFMA bf16 GEMM, double-buffered global_load_lds staging ----------
// C[m,n] = sum_k A[m,k] * Bt[n,k]. Tile BM x 128, BK=32, 2-phase pipeline.
constexpr int EPI_BIAS = 0, EPI_BIAS_ROW = 1, EPI_GELU = 2, EPI_ADD = 3, EPI_ADDROW0 = 4,
              EPI_QKV = 5;

template<int BM, int EPI, bool OUTBF, bool OUTBOTH>
__global__ __launch_bounds__(256)
void mfma_gemm_kernel(const unsigned short* __restrict__ A, const unsigned short* __restrict__ Bt,
                      const float* __restrict__ bias, const float* __restrict__ bias2,
                      const float* __restrict__ bias3, const float* __restrict__ extra,
                      float* __restrict__ C, unsigned short* __restrict__ Cbf,
                      int M, int N, int K,
                      long long sA, long long sB, long long sC)
{
  constexpr int NTt = (BM == 128) ? 4 : 2;   // 16-wide n-fragments per wave
  __shared__ unsigned short As[2][BM][4][8];
  __shared__ unsigned short Bs[2][128][4][8];
  const int tid = threadIdx.x;
  const int l = tid & 63, w = tid >> 6;
  const int wm = (BM == 128) ? (w & 1) * 64 : 0;
  const int wn = (BM == 128) ? (w >> 1) * 64 : w * 32;
  const int m0 = blockIdx.y * BM, n0 = blockIdx.x * 128;
  const unsigned short* Ap = A + (long long)blockIdx.z * sA;
  const unsigned short* Bp = Bt + (long long)blockIdx.z * sB;

  f32x4v acc[4][NTt];
  #pragma unroll
  for (int mt = 0; mt < 4; mt++)
    #pragma unroll
    for (int nt = 0; nt < NTt; nt++) acc[mt][nt] = {0.f, 0.f, 0.f, 0.f};

  const int c_ = l >> 4, rm = l & 15;
  int rrB[2], ggB[2];
  #pragma unroll
  for (int j = 0; j < 2; j++) {
    const int chunk = w * 128 + j * 64 + l;
    rrB[j] = chunk >> 2;
    ggB[j] = (chunk & 3) ^ ((rrB[j] >> 1) & 3);
  }
  int rrA = 0, ggA = 0;
  if constexpr (BM == 64) {
    const int chunkA = w * 64 + l;
    rrA = chunkA >> 2;
    ggA = (chunkA & 3) ^ ((rrA >> 1) & 3);
  }

  auto stage = [&](int bi, int k0) {
    if constexpr (BM == 128) {
      #pragma unroll
      for (int j = 0; j < 2; j++) {
        async16(Ap + (size_t)(m0 + rrB[j]) * K + k0 + ggB[j] * 8,
                &As[bi][0][0][0] + (size_t)(w * 128 + j * 64) * 8);
        async16(Bp + (size_t)(n0 + rrB[j]) * K + k0 + ggB[j] * 8,
                &Bs[bi][0][0][0] + (size_t)(w * 128 + j * 64) * 8);
      }
    } else {
      async16(Ap + (size_t)(m0 + rrA) * K + k0 + ggA * 8,
              &As[bi][0][0][0] + (size_t)(w * 64) * 8);
      #pragma unroll
      for (int j = 0; j < 2; j++)
        async16(Bp + (size_t)(n0 + rrB[j]) * K + k0 + ggB[j] * 8,
                &Bs[bi][0][0][0] + (size_t)(w * 128 + j * 64) * 8);
    }
  };

  stage(0, 0);
  __syncthreads();          // vmcnt(0) drain + barrier
  int cur = 0;
  const int sg = (rm >> 1) & 3;

  for (int k0 = 0; k0 < K; k0 += 32) {
    if (k0 + 32 < K) stage(cur ^ 1, k0 + 32);   // prefetch next tile (other buffer)

    frag af[4], bfr[NTt];
    #pragma unroll
    for (int mt = 0; mt < 4; mt++)
      af[mt] = *(const frag*)&As[cur][wm + mt * 16 + rm][c_ ^ sg][0];
    #pragma unroll
    for (int nt = 0; nt < NTt; nt++)
      bfr[nt] = *(const frag*)&Bs[cur][wn + nt * 16 + rm][c_ ^ sg][0];
    #pragma unroll
    for (int mt = 0; mt < 4; mt++)
      #pragma unroll
      for (int nt = 0; nt < NTt; nt++)
        acc[mt][nt] = __builtin_amdgcn_mfma_f32_16x16x32_bf16(af[mt], bfr[nt], acc[mt][nt], 0, 0, 0);

    __syncthreads();        // drains this iter's lgkm reads + next-tile vmcnt
    cur ^= 1;
  }

  float* Cp = C + (long long)blockIdx.z * sC;
  unsigned short* Cbp = Cbf + (long long)blockIdx.z * sC;
  #pragma unroll
  for (int mt = 0; mt < 4; mt++) {
    #pragma unroll
    for (int nt = 0; nt < NTt; nt++) {
      const int mq = m0 + wm + mt * 16 + c_ * 4;   // quad-base row (i = 0..3 below)
      const int n  = n0 + wn + nt * 16 + rm;       // C/D: col=lane&15
      if constexpr (EPI == EPI_QKV) {
        // n in [0,1024): q (fp32) | [1024,2048): k (fp32) | [2048,3072): V^T bf16
        const float* bp = (n < 1024) ? bias : ((n < 2048) ? bias2 : bias3);
        const float bv_ = ldf(bp + (n & 1023));
        const float r0 = acc[mt][nt][0] + bv_;
        const float r1 = acc[mt][nt][1] + bv_;
        const float r2 = acc[mt][nt][2] + bv_;
        const float r3 = acc[mt][nt][3] + bv_;
        if (n < 2048) {
          float* dst = Cp + (size_t)(n >> 10) * TD + (size_t)mq * Dc + (n & 1023);
          dst[0] = r0; dst[Dc] = r1; dst[2 * Dc] = r2; dst[3 * Dc] = r3;
        } else {
          ushort4 o;
          o.x = f2b(r0); o.y = f2b(r1); o.z = f2b(r2); o.w = f2b(r3);
          *(ushort4*)(Cbp + (size_t)(mq >> 11) * ((size_t)Lc * Dc)
                      + (size_t)(n - 2048) * Lc + (mq & (Lc - 1))) = o;
        }
      } else {
        #pragma unroll
        for (int i = 0; i < 4; i++) {
          const int m = mq + i;                     // C/D: row=(lane>>4)*4+reg
          float r = acc[mt][nt][i];
          if constexpr (EPI == EPI_BIAS || EPI == EPI_GELU || EPI == EPI_ADD || EPI == EPI_ADDROW0)
            r += ldf(bias + n);
          if constexpr (EPI == EPI_BIAS_ROW) r += ldf(bias + m);
          if constexpr (EPI == EPI_GELU)
            r = 0.5f * r * (1.0f + erff(r * 0.70710678118654752f));
          if constexpr (EPI == EPI_ADD) r += extra[(size_t)m * N + n];
          if constexpr (EPI == EPI_ADDROW0) r += extra[(size_t)(m >> 11) * ((size_t)Lc * Dc) + n];
          if constexpr (OUTBOTH) { Cp[(size_t)m * N + n] = r; Cbp[(size_t)m * N + n] = f2b(r); }
          else if constexpr (OUTBF) Cbp[(size_t)m * N + n] = f2b(r);
          else                      Cp[(size_t)m * N + n] = r;
        }
      }
    }
  }
}

// ---------- RoPE table fill ----------
__global__ __launch_bounds__(256)
void pe_fill_kernel(float* __restrict__ pet)
{
  const int gid = blockIdx.x * 256 + threadIdx.x;  // Lc*64
  const int l = gid >> 6, t = gid & 63;
  const int j = t & 31;
  const float wj = exp2f(-(float)j * (13.2877123795494f / 32.0f));
  const float ang = (float)l * wj;
  pet[gid] = (t < 32) ? cosf(ang) : sinf(ang);
}

// ---------- fused RoPE for Q and K: fp32 in, bf16 out ----------
// Q is pre-scaled by 0.125*log2(e) so flash-attn softmax works in base-2
// with zero per-element scale ops.
__global__ __launch_bounds__(256)
void rope2_kernel(const float* __restrict__ Qi, const float* __restrict__ Ki,
                  const float* __restrict__ pet,
                  unsigned short* __restrict__ Qo, unsigned short* __restrict__ Ko)
{
  int gid = blockIdx.x * 256 + threadIdx.x;  // 2*NT*Hc
  const int sel = gid >= NT * Hc;            // block-uniform (NT*Hc % 256 == 0)
  if (sel) gid -= NT * Hc;
  const float* X = sel ? Ki : Qi;
  unsigned short* O = sel ? Ko : Qo;
  const float scl = sel ? 1.0f : 0.125f * 1.44269504f;
  const int h = gid & (Hc - 1);
  const int token = gid >> 4;
  const int l = token & (Lc - 1);
  const float* p = X + (size_t)token * Dc + h * HDc;
  unsigned short* po = O + (size_t)token * Dc + h * HDc;
  const float* pr = pet + l * 64;
  float x[64], out[64];
  #pragma unroll
  for (int i = 0; i < 16; i++) *(float4*)&x[4*i] = *(const float4*)&p[4*i];
  #pragma unroll
  for (int u = 0; u < 32; u++) {
    const int base = (u < 16) ? (2 * u) : (32 + 2 * (u - 16));
    const float c = pr[base], s = pr[base + 1];
    out[u]      = (x[2*u] * c - x[2*u+1] * s) * scl;
    out[32 + u] = (x[2*u] * s + x[2*u+1] * c) * scl;
  }
  #pragma unroll
  for (int i = 0; i < 16; i++) {
    ushort4 o;
    o.x = f2b(out[4*i+0]); o.y = f2b(out[4*i+1]);
    o.z = f2b(out[4*i+2]); o.w = f2b(out[4*i+3]);
    *(ushort4*)&po[4*i] = o;
  }
}

// ---------- MFMA flash attention v10 ----------
// Lean v5 body (unconditional dbuf staging, runtime tile-skip only; no
// tile-norm machinery -- R8 showed it costs ~20us) + heavy-first 1-D grid
// (R9 showed +23us: ALiBi makes h=14/15 blocks 16x heavier; running all 64
// blocks of a heavy head concurrently spreads them over CUs AND shares the
// head's K/V panel in L2) + cvt_pk bf16 packing.
__global__ __launch_bounds__(256)
void flash_attn_mfma_kernel(const unsigned short* __restrict__ Q,
                            const unsigned short* __restrict__ K,
                            const unsigned short* __restrict__ VT,
                            unsigned short* __restrict__ O)
{
  __shared__ unsigned short Qs[64][8][8];
  __shared__ unsigned short Ks[2][64][8][8];
  __shared__ unsigned short Vt[2][64][8][8];
  __shared__ unsigned short Ps[64][72];
  const int tid = threadIdx.x;
  const int l = tid & 63, w = tid >> 6;
  const int lg = l >> 4, lm = l & 15;
  // heavy-first decode: h descends with bid/64; (b,q0) spread within
  const int bid = blockIdx.x;
  const int h = 15 - (bid >> 6);
  const int rem = bid & 63;
  const int b = rem & 1;
  const int q0 = (rem >> 1) * 64;
  const size_t rowbase = (size_t)b * Lc;
  const size_t vbase = (size_t)b * Lc * Dc;
  const int dbase = h * 64;
  const float sl2 = exp2f(-0.5f * (float)h) * 1.44269504f; // slope * log2(e)

  auto stageKV = [&](int bi, int k0s) {
    #pragma unroll
    for (int j = 0; j < 2; j++) {
      const int chunk = (w * 2 + j) * 64 + l;
      const int r = chunk >> 3, gsrc = (chunk & 7) ^ (r & 7);
      async16(K + (rowbase + k0s + r) * Dc + dbase + gsrc * 8,
              &Ks[bi][0][0][0] + (size_t)chunk * 8);
      async16(VT + vbase + (size_t)(dbase + r) * Lc + k0s + gsrc * 8,
              &Vt[bi][0][0][0] + (size_t)chunk * 8);
    }
  };

  // ---- stage Q + first K/V tile ----
  #pragma unroll
  for (int j = 0; j < 2; j++) {
    const int chunk = (w * 2 + j) * 64 + l;
    const int r = chunk >> 3, gsrc = (chunk & 7) ^ (r & 7);
    async16(Q + (rowbase + q0 + r) * Dc + dbase + gsrc * 8,
            &Qs[0][0][0] + (size_t)chunk * 8);
  }
  stageKV(0, 0);
  __syncthreads();
  frag qf[2];
  #pragma unroll
  for (int s = 0; s < 2; s++)
    qf[s] = *(const frag*)&Qs[w * 16 + lm][(s * 4 + lg) ^ (lm & 7)][0];

  // per-lane constants
  const float qg = (float)(q0 + w * 16 + lm);
  float koff[4][4];
  #pragma unroll
  for (int kt = 0; kt < 4; kt++)
    #pragma unroll
    for (int i = 0; i < 4; i++) koff[kt][i] = (float)(kt * 16 + lg * 4 + i);

  float m_i = -3.0e38f, l_i = 0.f;
  f32x4v acc_o[4];
  #pragma unroll
  for (int dt = 0; dt < 4; dt++) acc_o[dt] = {0.f, 0.f, 0.f, 0.f};

  int cur = 0;
  for (int k0 = 0; k0 < Lc; k0 += 64) {
    if (k0 + 64 < Lc) stageKV(cur ^ 1, k0 + 64);   // prefetch next tile

    // ---- S^T = K Q^T : rows k (64), cols q (16 of this wave) ----
    f32x4v st[4];
    #pragma unroll
    for (int kt = 0; kt < 4; kt++) st[kt] = {0.f, 0.f, 0.f, 0.f};
    __builtin_amdgcn_s_setprio(1);
    #pragma unroll
    for (int kt = 0; kt < 4; kt++) {
      #pragma unroll
      for (int s = 0; s < 2; s++) {
        frag kf = *(const frag*)&Ks[cur][kt * 16 + lm][(s * 4 + lg) ^ (lm & 7)][0];
        st[kt] = __builtin_amdgcn_mfma_f32_16x16x32_bf16(kf, qf[s], st[kt], 0, 0, 0);
      }
    }
    __builtin_amdgcn_s_setprio(0);

    // ---- bias by region (block-uniform branch) + row max ----
    const float qk0 = qg - (float)k0;
    float sv[4][4], tmax = -3.0e38f;
    if (k0 + 64 <= q0) {           // fully past: bias = sl2*(qg-kg), linear
      #pragma unroll
      for (int kt = 0; kt < 4; kt++)
        #pragma unroll
        for (int i = 0; i < 4; i++) {
          const float v = fmaf(sl2, qk0 - koff[kt][i], st[kt][i]);
          sv[kt][i] = v; tmax = fmaxf(tmax, v);
        }
    } else if (k0 <= q0) {         // diagonal tile: clamp at 0
      #pragma unroll
      for (int kt = 0; kt < 4; kt++)
        #pragma unroll
        for (int i = 0; i < 4; i++) {
          const float v = fmaf(sl2, fmaxf(qk0 - koff[kt][i], 0.f), st[kt][i]);
          sv[kt][i] = v; tmax = fmaxf(tmax, v);
        }
    } else {                       // fully future: bias = 0
      #pragma unroll
      for (int kt = 0; kt < 4; kt++)
        #pragma unroll
        for (int i = 0; i < 4; i++) {
          const float v = st[kt][i];
          sv[kt][i] = v; tmax = fmaxf(tmax, v);
        }
    }
    tmax = fmaxf(tmax, __shfl_xor(tmax, 16, 64));
    tmax = fmaxf(tmax, __shfl_xor(tmax, 32, 64));

    // ---- tile skip: contribution < 2^-27 per element -> negligible ----
    if (!__all(tmax < m_i - 27.0f)) {
      if (__any(tmax > m_i)) {     // exact skip: otherwise alpha == 1
        const float mnew = fmaxf(m_i, tmax);
        const float alpha = exp2f(m_i - mnew);
        m_i = mnew;
        l_i *= alpha;
        float aO[4];
        #pragma unroll
        for (int i = 0; i < 4; i++) aO[i] = __shfl(alpha, lg * 4 + i, 64);
        #pragma unroll
        for (int dt = 0; dt < 4; dt++)
          #pragma unroll
          for (int i = 0; i < 4; i++) acc_o[dt][i] *= aO[i];
      }
      float rsum = 0.f;
      const int qrow = w * 16 + lm;
      #pragma unroll
      for (int kt = 0; kt < 4; kt++) {
        const float p0 = exp2f(sv[kt][0] - m_i), p1 = exp2f(sv[kt][1] - m_i);
        const float p2 = exp2f(sv[kt][2] - m_i), p3 = exp2f(sv[kt][3] - m_i);
        rsum += (p0 + p1) + (p2 + p3);
        unsigned int w0, w1;       // packed bf16 pairs (lo=first arg)
        asm("v_cvt_pk_bf16_f32 %0, %1, %2" : "=v"(w0) : "v"(p0), "v"(p1));
        asm("v_cvt_pk_bf16_f32 %0, %1, %2" : "=v"(w1) : "v"(p2), "v"(p3));
        uint2 pw; pw.x = w0; pw.y = w1;
        *(uint2*)&Ps[qrow][kt * 16 + lg * 4] = pw;   // 4 consecutive k
      }
      rsum += __shfl_xor(rsum, 16, 64);
      rsum += __shfl_xor(rsum, 32, 64);
      l_i += rsum;

      // ---- O += P V (Ps rows wave-private; same-wave DS order suffices) ----
      __builtin_amdgcn_s_setprio(1);
      #pragma unroll
      for (int c = 0; c < 2; c++) {
        frag ap = *(const frag*)&Ps[w * 16 + lm][c * 32 + lg * 8];
        #pragma unroll
        for (int dt = 0; dt < 4; dt++) {
          frag bv = *(const frag*)&Vt[cur][dt * 16 + lm][(c * 4 + lg) ^ (lm & 7)][0];
          acc_o[dt] = __builtin_amdgcn_mfma_f32_16x16x32_bf16(ap, bv, acc_o[dt], 0, 0, 0);
        }
      }
      __builtin_amdgcn_s_setprio(0);
    }

    __syncthreads();    // drains this iter's lgkm reads + next-tile vmcnt
    cur ^= 1;
  }

  // ---- epilogue: normalize, bounce through Ps, coalesced store ----
  float lO[4];
  #pragma unroll
  for (int i = 0; i < 4; i++) lO[i] = 1.0f / __shfl(l_i, lg * 4 + i, 64);
  #pragma unroll
  for (int dt = 0; dt < 4; dt++)
    #pragma unroll
    for (int i = 0; i < 4; i++)
      Ps[w * 16 + lg * 4 + i][dt * 16 + lm] = f2b(acc_o[dt][i] * lO[i]);
  __syncthreads();
  #pragma unroll
  for (int j = 0; j < 2; j++) {
    const int chunk = (w * 2 + j) * 64 + l;
    const int r = chunk >> 3, g = chunk & 7;
    alignas(16) unsigned short tmp[8];
    #pragma unroll
    for (int t = 0; t < 8; t++) tmp[t] = Ps[r][g * 8 + t];
    *(uint4*)(O + (rowbase + q0 + r) * Dc + dbase + g * 8) = *(uint4*)tmp;
  }
}

// ---------- fused: mem1 = RES + ln(X;n1) -> fp32; hln = ln(mem1;cln) -> bf16 ----
__global__ __launch_bounds__(256)
void ln_res_cln_kernel(const float* __restrict__ X, const float* __restrict__ RES,
                       const float* __restrict__ g1, const float* __restrict__ b1,
                       const float* __restrict__ g2, const float* __restrict__ b2,
                       float* __restrict__ OUT1, unsigned short* __restrict__ OUT2)
{
  __shared__ float red4[4];
  const int row = blockIdx.x, tid = threadIdx.x;
  const size_t base = (size_t)row * Dc + tid * 4;
  const float4 xv = *(const float4*)(X + base);
  float s = xv.x + xv.y + xv.z + xv.w;
  s = block_sum(s, red4);
  const float mean = s * (1.0f / Dc);
  const float d0 = xv.x-mean, d1 = xv.y-mean, d2 = xv.z-mean, d3 = xv.w-mean;
  float ss = d0*d0 + d1*d1 + d2*d2 + d3*d3;
  ss = block_sum(ss, red4);
  const float rstd = rsqrtf(ss * (1.0f / Dc) + 1e-5f);
  const int c = tid * 4;
  const float4 rv = *(const float4*)(RES + base);
  float y0 = rv.x + d0*rstd*ldf(g1+c+0) + ldf(b1+c+0);
  float y1 = rv.y + d1*rstd*ldf(g1+c+1) + ldf(b1+c+1);
  float y2 = rv.z + d2*rstd*ldf(g1+c+2) + ldf(b1+c+2);
  float y3 = rv.w + d3*rstd*ldf(g1+c+3) + ldf(b1+c+3);
  *(float4*)(OUT1 + base) = make_float4(y0, y1, y2, y3);
  float s2 = y0 + y1 + y2 + y3;
  s2 = block_sum(s2, red4);
  const float mean2 = s2 * (1.0f / Dc);
  const float e0 = y0-mean2, e1 = y1-mean2, e2 = y2-mean2, e3 = y3-mean2;
  float ss2 = e0*e0 + e1*e1 + e2*e2 + e3*e3;
  ss2 = block_sum(ss2, red4);
  const float rstd2 = rsqrtf(ss2 * (1.0f / Dc) + 1e-5f);
  ushort4 o;
  o.x = f2b(e0*rstd2*ldf(g2+c+0) + ldf(b2+c+0));
  o.y = f2b(e1*rstd2*ldf(g2+c+1) + ldf(b2+c+1));
  o.z = f2b(e2*rstd2*ldf(g2+c+2) + ldf(b2+c+2));
  o.w = f2b(e3*rstd2*ldf(g2+c+3) + ldf(b2+c+3));
  *(ushort4*)(OUT2 + base) = o;
}

__global__ __launch_bounds__(256)   // OUT = ln(X + Y)
void ln_sum_kernel(const float* __restrict__ X, const float* __restrict__ Y,
                   const float* __restrict__ g, const float* __restrict__ be,
                   float* __restrict__ OUT)
{
  __shared__ float red4[4];
  const int row = blockIdx.x, tid = threadIdx.x;
  const size_t base = (size_t)row * Dc + tid * 4;
  const float4 xv = *(const float4*)(X + base);
  const float4 yv = *(const float4*)(Y + base);
  const float x0 = xv.x+yv.x, x1 = xv.y+yv.y, x2 = xv.z+yv.z, x3 = xv.w+yv.w;
  float s = x0 + x1 + x2 + x3;
  s = block_sum(s, red4);
  const float mean = s * (1.0f / Dc);
  const float d0 = x0-mean, d1 = x1-mean, d2 = x2-mean, d3 = x3-mean;
  float ss = d0*d0 + d1*d1 + d2*d2 + d3*d3;
  ss = block_sum(ss, red4);
  const float rstd = rsqrtf(ss * (1.0f / Dc) + 1e-5f);
  const int c = tid * 4;
  float4 o;
  o.x = d0*rstd*ldf(g+c+0) + ldf(be+c+0);
  o.y = d1*rstd*ldf(g+c+1) + ldf(be+c+1);
  o.z = d2*rstd*ldf(g+c+2) + ldf(be+c+2);
  o.w = d3*rstd*ldf(g+c+3) + ldf(be+c+3);
  *(float4*)(OUT + base) = o;
}

// ---------- depthwise conv K=5 with fused GLU input (+bias, bn-scale,
// hardswish), bf16 out. Reads the pw1 output H1 [token][2*Dc] directly:
// tap value = H1[lp][d] * sigmoid(H1[lp][d+Dc]). Removes the separate GLU
// pass (16MB write + 16MB read + 1 launch); extra sigmoids ride the trans
// pipe under the loads (kernel is memory-bound).
__global__ __launch_bounds__(256)
void dwconv_glu_bf16_kernel(const float* __restrict__ H1, const float* __restrict__ w,
                            const float* __restrict__ wb, const float* __restrict__ gn,
                            const float* __restrict__ bb, unsigned short* __restrict__ OUT)
{
  const int gid = blockIdx.x * 256 + threadIdx.x;
  const int d = gid & (Dc - 1);
  const int l = (gid >> 10) & (Lc - 1);
  const int b = gid >> 21;
  const size_t rowb = (size_t)b * Lc;
  float acc = ldf(wb + d);
  #pragma unroll
  for (int s = 0; s < 5; s++) {
    const int lp = l + 2 - s;
    if (lp >= 0 && lp < Lc) {
      const float* p = H1 + (rowb + lp) * (size_t)(2 * Dc) + d;
      const float a = p[0], g = p[Dc];
      acc += ldf(w + d * 5 + s) * (a / (1.0f + expf(-g)));
    }
  }
  const float rs = rsqrtf(1.0f + 1e-5f);
  const float t = acc * rs * ldf(gn + d) + ldf(bb + d);
  OUT[gid] = f2b(t * fminf(fmaxf(t + 3.0f, 0.0f), 6.0f) * (1.0f / 6.0f));
}

// =====================================================================
extern "C" void kernel_launch(void* const* d_in, const int* in_sizes, int n_in,
                              void* d_out, int out_size, void* d_ws, size_t ws_size,
                              hipStream_t stream) {
  (void)in_sizes; (void)n_in; (void)out_size; (void)ws_size;
  const float* mem    = (const float*)d_in[0];
  const float* wq     = (const float*)d_in[1];
  const float* bq     = (const float*)d_in[2];
  const float* wk     = (const float*)d_in[3];
  const float* bk     = (const float*)d_in[4];
  const float* wv     = (const float*)d_in[5];
  const float* bv     = (const float*)d_in[6];
  const float* wo     = (const float*)d_in[7];
  const float* bo     = (const float*)d_in[8];
  const float* n1g    = (const float*)d_in[9];
  const float* n1b    = (const float*)d_in[10];
  const float* clng   = (const float*)d_in[11];
  const float* clnb   = (const float*)d_in[12];
  const float* pw1w   = (const float*)d_in[13];
  const float* pw1b   = (const float*)d_in[14];
  const float* dww    = (const float*)d_in[15];
  const float* dwb    = (const float*)d_in[16];
  const float* bng    = (const float*)d_in[17];
  const float* bnb    = (const float*)d_in[18];
  const float* pw2w   = (const float*)d_in[19];
  const float* pw2b   = (const float*)d_in[20];
  const float* projw  = (const float*)d_in[21];
  const float* projb  = (const float*)d_in[22];
  const float* proj2w = (const float*)d_in[23];
  const float* proj2b = (const float*)d_in[24];
  const float* lin1w  = (const float*)d_in[25];
  const float* lin1b  = (const float*)d_in[26];
  const float* lin2w  = (const float*)d_in[27];
  const float* lin2b  = (const float*)d_in[28];
  const float* n3g    = (const float*)d_in[29];
  const float* n3b    = (const float*)d_in[30];
  float* out = (float*)d_out;

  char* base = (char*)d_ws;
  float* qb   = (float*)base;          // q fp32 -> tgt2 fp32
  float* kb   = qb + TD;               // k fp32 -> mem1
  float* big1 = kb + TD;               // h1 lo -> mem2 fp32
  float* big2 = big1 + TD;             // h1 hi -> conv_out
  float* ob   = big2 + TD;             // ffout
  unsigned short* abf  = (unsigned short*)(base + 5 * TD * 4);  // bf16 hub
  unsigned short* qbf  = abf + TD;     // rope-q -> mem2 bf16
  unsigned short* kbf  = qbf + TD;
  unsigned short* vtb  = kbf + TD;     // V^T bf16  [b][1024 d][2048 l]
  unsigned short* m1T  = vtb + TD;
  unsigned short* ffbbf= m1T + TD;     // NT*FF = 4*TD shorts
  unsigned short* wt   = ffbbf + 4 * TD;
  unsigned short* wqT    = wt;            // [1024][1024] } contiguous => [3072][1024] fused QKV B^T
  unsigned short* wkT    = wqT + MEG;
  unsigned short* wvT    = wkT + MEG;
  unsigned short* woT    = wvT + MEG;
  unsigned short* pw1T   = woT + MEG;     // [2048][1024]
  unsigned short* pw2T   = pw1T + 2*MEG;  // [1024][1024]
  unsigned short* proj2T = pw2T + MEG;    // [1024][1024]
  unsigned short* projwT = proj2T + MEG;  // [2048][2048]
  unsigned short* lin1T  = projwT + 4*MEG;// [4096][1024]
  unsigned short* lin2T  = lin1T + 4*MEG; // [1024][4096]
  float* pet = (float*)(lin2T + 4*MEG);   // [2048][64] rope table

  const dim3 blk(256);
  const long long LD = (long long)Lc * Dc;

  // ---- fused weight transposes + rope table ----
  TPack tp;
  const float* tin[10]  = {wq, wk, wv, wo, pw1w, pw2w, proj2w, projw, lin1w, lin2w};
  unsigned short* tout[10] = {wqT, wkT, wvT, woT, pw1T, pw2T, proj2T, projwT, lin1T, lin2T};
  const int tR[10] = {1024,1024,1024,1024,1024,1024,1024,2048,1024,4096};
  const int tC[10] = {1024,1024,1024,1024,2048,1024,1024,2048,4096,1024};
  int startAcc = 0;
  for (int i = 0; i < 10; i++) {
    tp.in[i] = tin[i]; tp.out[i] = tout[i];
    tp.R[i] = tR[i]; tp.C[i] = tC[i]; tp.tx[i] = tC[i] / 64;
    tp.start[i] = startAcc;
    startAcc += (tR[i] / 64) * (tC[i] / 64);
  }
  fused_transpose_kernel<<<dim3(startAcc), blk, 0, stream>>>(tp);
  pe_fill_kernel<<<dim3(Lc * 64 / 256), blk, 0, stream>>>(pet);

  // ---- attention ----
  convert_bf16_kernel<<<dim3((unsigned)(TD/1024)),blk,0,stream>>>(mem, abf);
  // fused QKV: N=3072, q->qb fp32, k->kb fp32, V->vtb transposed bf16 directly
  mfma_gemm_kernel<128,EPI_QKV,false,false><<<dim3(24,32,1),blk,0,stream>>>(
      abf, wqT, bq, bk, bv, nullptr, qb, vtb, NT, 3*Dc, Dc, 0, 0, 0);
  rope2_kernel<<<dim3(2*NT*Hc/256),blk,0,stream>>>(qb, kb, pet, qbf, kbf);
  flash_attn_mfma_kernel<<<dim3(1024),blk,0,stream>>>(qbf,kbf,vtb,abf);
  mfma_gemm_kernel<64,EPI_BIAS,false,false><<<dim3(8,64,1),blk,0,stream>>>(
      abf,woT,bo,nullptr,nullptr,nullptr,qb,nullptr,NT,Dc,Dc,0,0,0);
  // mem1 (fp32 -> kb) and ln(mem1) (bf16 -> abf) in one pass
  ln_res_cln_kernel<<<dim3(NT),blk,0,stream>>>(qb, mem, n1g, n1b, clng, clnb, kb, abf);

  // ---- conv block (GLU fused into dwconv) ----
  mfma_gemm_kernel<128,EPI_BIAS,false,false><<<dim3(16,32,1),blk,0,stream>>>(
      abf,pw1T,pw1b,nullptr,nullptr,nullptr,big1,nullptr,NT,2*Dc,Dc,0,0,0);
  dwconv_glu_bf16_kernel<<<dim3((unsigned)(TD/256)),blk,0,stream>>>(big1, dww, dwb, bng, bnb, abf);
  mfma_gemm_kernel<64,EPI_ADDROW0,false,false><<<dim3(8,64,1),blk,0,stream>>>(
      abf,pw2T,pw2b,nullptr,nullptr,kb,big2,nullptr,NT,Dc,Dc,0,0,0);

  // ---- proj path ----
  transpose_convert_kernel<<<dim3(16,32,2),blk,0,stream>>>(kb, m1T, 2048, 1024, LD, LD);
  mfma_gemm_kernel<64,EPI_BIAS_ROW,true,false><<<dim3(8,32,2),blk,0,stream>>>(
      projwT,m1T,projb,nullptr,nullptr,nullptr,nullptr,abf,Lc,Dc,Lc,0,LD,LD);
  // mem2 = proj@proj2 + conv_out: fp32 -> big1 AND bf16 -> qbf (feeds lin1)
  mfma_gemm_kernel<64,EPI_ADD,false,true><<<dim3(8,64,1),blk,0,stream>>>(
      abf,proj2T,proj2b,nullptr,nullptr,big2,big1,qbf,NT,Dc,Dc,0,0,0);

  // ---- feed-forward ----
  mfma_gemm_kernel<128,EPI_GELU,true,false><<<dim3(32,32,1),blk,0,stream>>>(
      qbf,lin1T,lin1b,nullptr,nullptr,nullptr,nullptr,ffbbf,NT,FFc,Dc,0,0,0);
  mfma_gemm_kernel<64,EPI_BIAS,false,false><<<dim3(8,64,1),blk,0,stream>>>(
      ffbbf,lin2T,lin2b,nullptr,nullptr,nullptr,ob,nullptr,NT,Dc,FFc,0,0,0);

  // ---- final: out = ln(mem2 + ffout) ----
  ln_sum_kernel<<<dim3(NT),blk,0,stream>>>(big1, ob, n3g, n3b, out);
}

// Round 11
// 632.176 us; speedup vs baseline: 1.0825x; 1.0092x over previous
//
#include <hip/hip_runtime.h>
#include <hip/hip_bf16.h>
#include <math.h>

constexpr int Bc = 2, Lc = 2048, Dc = 1024, Hc = 16, HDc = 64, FFc = 4096;
constexpr int NT = Bc * Lc;              // 4096 tokens
constexpr size_t TD = (size_t)NT * Dc;   // 4194304 elements per [B,L,D] tensor
constexpr size_t MEG = 1024 * 1024;

__device__ __forceinline__ float ldf(const float* p) { return *p; }
__device__ __forceinline__ unsigned short f2b(float f) {
  __hip_bfloat16 h = __float2bfloat16(f);
  return *reinterpret_cast<unsigned short*>(&h);
}

using frag   = __attribute__((ext_vector_type(8))) short;   // 8 bf16 (4 VGPRs)
using f32x4v = __attribute__((ext_vector_type(4))) float;   // MFMA C/D

// async global -> LDS, 16B per lane; LDS dest = wave-uniform base + lane*16
__device__ __forceinline__ void async16(const unsigned short* g, unsigned short* l) {
  __builtin_amdgcn_global_load_lds(
      (const __attribute__((address_space(1))) unsigned int*)g,
      (__attribute__((address_space(3))) unsigned int*)l, 16, 0, 0);
}

// ---------- block reductions (blockDim.x == 256 = 4 waves) ----------
__device__ __forceinline__ float block_sum(float v, float* red) {
  const int lane = threadIdx.x & 63, w = threadIdx.x >> 6;
  #pragma unroll
  for (int o = 32; o > 0; o >>= 1) v += __shfl_down(v, o, 64);
  __syncthreads();
  if (lane == 0) red[w] = v;
  __syncthreads();
  return red[0] + red[1] + red[2] + red[3];
}

// ---------- fp32 -> bf16 convert ----------
__global__ __launch_bounds__(256)
void convert_bf16_kernel(const float* __restrict__ IN, unsigned short* __restrict__ OUT)
{
  const size_t gid = (size_t)blockIdx.x * 256 + threadIdx.x;
  const float4 v = *(const float4*)(IN + gid * 4);
  ushort4 o;
  o.x = f2b(v.x); o.y = f2b(v.y); o.z = f2b(v.z); o.w = f2b(v.w);
  *(ushort4*)(OUT + gid * 4) = o;
}

// ---------- fp32 [R,C] -> bf16 [C,R] transpose-convert (z-batched) ----------
__global__ __launch_bounds__(256)
void transpose_convert_kernel(const float* __restrict__ IN, unsigned short* __restrict__ OUT,
                              int R, int C, long long sIn, long long sOut)
{
  __shared__ float tile[64][65];
  const int t = threadIdx.x;
  const float* in = IN + (long long)blockIdx.z * sIn;
  unsigned short* out = OUT + (long long)blockIdx.z * sOut;
  const int r0 = blockIdx.y * 64, c0 = blockIdx.x * 64;
  #pragma unroll
  for (int i = 0; i < 4; i++) {
    const int r = (t >> 4) + i * 16, c4 = (t & 15) * 4;
    const float4 v = *(const float4*)(in + (size_t)(r0 + r) * C + c0 + c4);
    tile[r][c4+0] = v.x; tile[r][c4+1] = v.y; tile[r][c4+2] = v.z; tile[r][c4+3] = v.w;
  }
  __syncthreads();
  #pragma unroll
  for (int i = 0; i < 4; i++) {
    const int cc = (t >> 4) + i * 16, rr4 = (t & 15) * 4;
    ushort4 o;
    o.x = f2b(tile[rr4+0][cc]); o.y = f2b(tile[rr4+1][cc]);
    o.z = f2b(tile[rr4+2][cc]); o.w = f2b(tile[rr4+3][cc]);
    *(ushort4*)(out + (size_t)(c0 + cc) * R + r0 + rr4) = o;
  }
}

// ---------- fused weight transposes: 10 segments in one launch ----------
struct TPack {
  const float* in[10]; unsigned short* out[10];
  int R[10], C[10], tx[10], start[10];
};
__global__ __launch_bounds__(256)
void fused_transpose_kernel(TPack p)
{
  __shared__ float tile[64][65];
  const int bid = blockIdx.x;
  int s = 0;
  #pragma unroll
  for (int i = 1; i < 10; i++) s = (bid >= p.start[i]) ? i : s;
  const float* in = p.in[s];
  unsigned short* out = p.out[s];
  const int R = p.R[s], C = p.C[s];
  const int local = bid - p.start[s];
  const int bx = local % p.tx[s], by = local / p.tx[s];
  const int r0 = by * 64, c0 = bx * 64;
  const int t = threadIdx.x;
  #pragma unroll
  for (int i = 0; i < 4; i++) {
    const int r = (t >> 4) + i * 16, c4 = (t & 15) * 4;
    const float4 v = *(const float4*)(in + (size_t)(r0 + r) * C + c0 + c4);
    tile[r][c4+0] = v.x; tile[r][c4+1] = v.y; tile[r][c4+2] = v.z; tile[r][c4+3] = v.w;
  }
  __syncthreads();
  #pragma unroll
  for (int i = 0; i < 4; i++) {
    const int cc = (t >> 4) + i * 16, rr4 = (t & 15) * 4;
    ushort4 o;
    o.x = f2b(tile[rr4+0][cc]); o.y = f2b(tile[rr4+1][cc]);
    o.z = f2b(tile[rr4+2][cc]); o.w = f2b(tile[rr4+3][cc]);
    *(ushort4*)(out + (size_t)(c0 + cc) * R + r0 + rr4) = o;
  }
}

// ---------- MFMA bf16 GEMM, double-buffered global_load_lds staging ----------
// C[m,n] = sum_k A[m,k] * Bt[n,k]. Tile BM x 128, BK=32, 2-phase pipeline.
// XCD-aware bijective block swizzle (T1): same-XCD blocks become contiguous
// row-major so A panels are reused within one XCD's private L2 instead of
// being fetched into all 8. All grids here have nwg % 8 == 0 (required for
// bijectivity).
constexpr int EPI_BIAS = 0, EPI_BIAS_ROW = 1, EPI_GELU = 2, EPI_ADD = 3, EPI_ADDROW0 = 4,
              EPI_QKV = 5;

template<int BM, int EPI, bool OUTBF, bool OUTBOTH>
__global__ __launch_bounds__(256)
void mfma_gemm_kernel(const unsigned short* __restrict__ A, const unsigned short* __restrict__ Bt,
                      const float* __restrict__ bias, const float* __restrict__ bias2,
                      const float* __restrict__ bias3, const float* __restrict__ extra,
                      float* __restrict__ C, unsigned short* __restrict__ Cbf,
                      int M, int N, int K,
                      long long sA, long long sB, long long sC)
{
  constexpr int NTt = (BM == 128) ? 4 : 2;   // 16-wide n-fragments per wave
  __shared__ unsigned short As[2][BM][4][8];
  __shared__ unsigned short Bs[2][128][4][8];
  const int tid = threadIdx.x;
  const int l = tid & 63, w = tid >> 6;
  const int wm = (BM == 128) ? (w & 1) * 64 : 0;
  const int wn = (BM == 128) ? (w >> 1) * 64 : w * 32;
  // XCD swizzle: orig -> (orig%8)*(nwg/8) + orig/8 (bijective, nwg%8==0)
  const int nwg = gridDim.x * gridDim.y;
  const int orig = blockIdx.y * gridDim.x + blockIdx.x;
  const int nb = (orig & 7) * (nwg >> 3) + (orig >> 3);
  const int bx = nb % gridDim.x, by = nb / gridDim.x;
  const int m0 = by * BM, n0 = bx * 128;
  const unsigned short* Ap = A + (long long)blockIdx.z * sA;
  const unsigned short* Bp = Bt + (long long)blockIdx.z * sB;

  f32x4v acc[4][NTt];
  #pragma unroll
  for (int mt = 0; mt < 4; mt++)
    #pragma unroll
    for (int nt = 0; nt < NTt; nt++) acc[mt][nt] = {0.f, 0.f, 0.f, 0.f};

  const int c_ = l >> 4, rm = l & 15;
  int rrB[2], ggB[2];
  #pragma unroll
  for (int j = 0; j < 2; j++) {
    const int chunk = w * 128 + j * 64 + l;
    rrB[j] = chunk >> 2;
    ggB[j] = (chunk & 3) ^ ((rrB[j] >> 1) & 3);
  }
  int rrA = 0, ggA = 0;
  if constexpr (BM == 64) {
    const int chunkA = w * 64 + l;
    rrA = chunkA >> 2;
    ggA = (chunkA & 3) ^ ((rrA >> 1) & 3);
  }

  auto stage = [&](int bi, int k0) {
    if constexpr (BM == 128) {
      #pragma unroll
      for (int j = 0; j < 2; j++) {
        async16(Ap + (size_t)(m0 + rrB[j]) * K + k0 + ggB[j] * 8,
                &As[bi][0][0][0] + (size_t)(w * 128 + j * 64) * 8);
        async16(Bp + (size_t)(n0 + rrB[j]) * K + k0 + ggB[j] * 8,
                &Bs[bi][0][0][0] + (size_t)(w * 128 + j * 64) * 8);
      }
    } else {
      async16(Ap + (size_t)(m0 + rrA) * K + k0 + ggA * 8,
              &As[bi][0][0][0] + (size_t)(w * 64) * 8);
      #pragma unroll
      for (int j = 0; j < 2; j++)
        async16(Bp + (size_t)(n0 + rrB[j]) * K + k0 + ggB[j] * 8,
                &Bs[bi][0][0][0] + (size_t)(w * 128 + j * 64) * 8);
    }
  };

  stage(0, 0);
  __syncthreads();          // vmcnt(0) drain + barrier
  int cur = 0;
  const int sg = (rm >> 1) & 3;

  for (int k0 = 0; k0 < K; k0 += 32) {
    if (k0 + 32 < K) stage(cur ^ 1, k0 + 32);   // prefetch next tile (other buffer)

    frag af[4], bfr[NTt];
    #pragma unroll
    for (int mt = 0; mt < 4; mt++)
      af[mt] = *(const frag*)&As[cur][wm + mt * 16 + rm][c_ ^ sg][0];
    #pragma unroll
    for (int nt = 0; nt < NTt; nt++)
      bfr[nt] = *(const frag*)&Bs[cur][wn + nt * 16 + rm][c_ ^ sg][0];
    #pragma unroll
    for (int mt = 0; mt < 4; mt++)
      #pragma unroll
      for (int nt = 0; nt < NTt; nt++)
        acc[mt][nt] = __builtin_amdgcn_mfma_f32_16x16x32_bf16(af[mt], bfr[nt], acc[mt][nt], 0, 0, 0);

    __syncthreads();        // drains this iter's lgkm reads + next-tile vmcnt
    cur ^= 1;
  }

  float* Cp = C + (long long)blockIdx.z * sC;
  unsigned short* Cbp = Cbf + (long long)blockIdx.z * sC;
  #pragma unroll
  for (int mt = 0; mt < 4; mt++) {
    #pragma unroll
    for (int nt = 0; nt < NTt; nt++) {
      const int mq = m0 + wm + mt * 16 + c_ * 4;   // quad-base row (i = 0..3 below)
      const int n  = n0 + wn + nt * 16 + rm;       // C/D: col=lane&15
      if constexpr (EPI == EPI_QKV) {
        // n in [0,1024): q (fp32) | [1024,2048): k (fp32) | [2048,3072): V^T bf16
        const float* bp = (n < 1024) ? bias : ((n < 2048) ? bias2 : bias3);
        const float bv_ = ldf(bp + (n & 1023));
        const float r0 = acc[mt][nt][0] + bv_;
        const float r1 = acc[mt][nt][1] + bv_;
        const float r2 = acc[mt][nt][2] + bv_;
        const float r3 = acc[mt][nt][3] + bv_;
        if (n < 2048) {
          float* dst = Cp + (size_t)(n >> 10) * TD + (size_t)mq * Dc + (n & 1023);
          dst[0] = r0; dst[Dc] = r1; dst[2 * Dc] = r2; dst[3 * Dc] = r3;
        } else {
          ushort4 o;
          o.x = f2b(r0); o.y = f2b(r1); o.z = f2b(r2); o.w = f2b(r3);
          *(ushort4*)(Cbp + (size_t)(mq >> 11) * ((size_t)Lc * Dc)
                      + (size_t)(n - 2048) * Lc + (mq & (Lc - 1))) = o;
        }
      } else {
        #pragma unroll
        for (int i = 0; i < 4; i++) {
          const int m = mq + i;                     // C/D: row=(lane>>4)*4+reg
          float r = acc[mt][nt][i];
          if constexpr (EPI == EPI_BIAS || EPI == EPI_GELU || EPI == EPI_ADD || EPI == EPI_ADDROW0)
            r += ldf(bias + n);
          if constexpr (EPI == EPI_BIAS_ROW) r += ldf(bias + m);
          if constexpr (EPI == EPI_GELU)
            r = 0.5f * r * (1.0f + erff(r * 0.70710678118654752f));
          if constexpr (EPI == EPI_ADD) r += extra[(size_t)m * N + n];
          if constexpr (EPI == EPI_ADDROW0) r += extra[(size_t)(m >> 11) * ((size_t)Lc * Dc) + n];
          if constexpr (OUTBOTH) { Cp[(size_t)m * N + n] = r; Cbp[(size_t)m * N + n] = f2b(r); }
          else if constexpr (OUTBF) Cbp[(size_t)m * N + n] = f2b(r);
          else                      Cp[(size_t)m * N + n] = r;
        }
      }
    }
  }
}

// ---------- RoPE table fill ----------
__global__ __launch_bounds__(256)
void pe_fill_kernel(float* __restrict__ pet)
{
  const int gid = blockIdx.x * 256 + threadIdx.x;  // Lc*64
  const int l = gid >> 6, t = gid & 63;
  const int j = t & 31;
  const float wj = exp2f(-(float)j * (13.2877123795494f / 32.0f));
  const float ang = (float)l * wj;
  pet[gid] = (t < 32) ? cosf(ang) : sinf(ang);
}

// ---------- fused RoPE for Q and K: fp32 in, bf16 out ----------
// Q is pre-scaled by 0.125*log2(e) so flash-attn softmax works in base-2
// with zero per-element scale ops.
__global__ __launch_bounds__(256)
void rope2_kernel(const float* __restrict__ Qi, const float* __restrict__ Ki,
                  const float* __restrict__ pet,
                  unsigned short* __restrict__ Qo, unsigned short* __restrict__ Ko)
{
  int gid = blockIdx.x * 256 + threadIdx.x;  // 2*NT*Hc
  const int sel = gid >= NT * Hc;            // block-uniform (NT*Hc % 256 == 0)
  if (sel) gid -= NT * Hc;
  const float* X = sel ? Ki : Qi;
  unsigned short* O = sel ? Ko : Qo;
  const float scl = sel ? 1.0f : 0.125f * 1.44269504f;
  const int h = gid & (Hc - 1);
  const int token = gid >> 4;
  const int l = token & (Lc - 1);
  const float* p = X + (size_t)token * Dc + h * HDc;
  unsigned short* po = O + (size_t)token * Dc + h * HDc;
  const float* pr = pet + l * 64;
  float x[64], out[64];
  #pragma unroll
  for (int i = 0; i < 16; i++) *(float4*)&x[4*i] = *(const float4*)&p[4*i];
  #pragma unroll
  for (int u = 0; u < 32; u++) {
    const int base = (u < 16) ? (2 * u) : (32 + 2 * (u - 16));
    const float c = pr[base], s = pr[base + 1];
    out[u]      = (x[2*u] * c - x[2*u+1] * s) * scl;
    out[32 + u] = (x[2*u] * s + x[2*u+1] * c) * scl;
  }
  #pragma unroll
  for (int i = 0; i < 16; i++) {
    ushort4 o;
    o.x = f2b(out[4*i+0]); o.y = f2b(out[4*i+1]);
    o.z = f2b(out[4*i+2]); o.w = f2b(out[4*i+3]);
    *(ushort4*)&po[4*i] = o;
  }
}

// ---------- MFMA flash attention v11 ----------
// v10 body + LDS diet: Qs is dead after the prologue (qf registers) and both
// Qs and Ps are wave-private over the same row range, so they share ONE 8KB
// buffer QP. Ps's +8-pad is replaced by an XOR swizzle of the 16B unit index
// (unit ^ (row&7)) applied at store AND read -- same flat-column mapping as
// before, conflict-free, zero padding. LDS 50176 -> 40960 B = exactly
// 4 blocks/CU.
__global__ __launch_bounds__(256)
void flash_attn_mfma_kernel(const unsigned short* __restrict__ Q,
                            const unsigned short* __restrict__ K,
                            const unsigned short* __restrict__ VT,
                            unsigned short* __restrict__ O)
{
  __shared__ unsigned short QP[64][64];       // Qs (prologue) then Ps (loop)
  __shared__ unsigned short Ks[2][64][8][8];
  __shared__ unsigned short Vt[2][64][8][8];
  const int tid = threadIdx.x;
  const int l = tid & 63, w = tid >> 6;
  const int lg = l >> 4, lm = l & 15;
  // heavy-first decode: h descends with bid/64; (b,q0) spread within
  const int bid = blockIdx.x;
  const int h = 15 - (bid >> 6);
  const int rem = bid & 63;
  const int b = rem & 1;
  const int q0 = (rem >> 1) * 64;
  const size_t rowbase = (size_t)b * Lc;
  const size_t vbase = (size_t)b * Lc * Dc;
  const int dbase = h * 64;
  const float sl2 = exp2f(-0.5f * (float)h) * 1.44269504f; // slope * log2(e)

  auto stageKV = [&](int bi, int k0s) {
    #pragma unroll
    for (int j = 0; j < 2; j++) {
      const int chunk = (w * 2 + j) * 64 + l;
      const int r = chunk >> 3, gsrc = (chunk & 7) ^ (r & 7);
      async16(K + (rowbase + k0s + r) * Dc + dbase + gsrc * 8,
              &Ks[bi][0][0][0] + (size_t)chunk * 8);
      async16(VT + vbase + (size_t)(dbase + r) * Lc + k0s + gsrc * 8,
              &Vt[bi][0][0][0] + (size_t)chunk * 8);
    }
  };

  // ---- stage Q (into QP) + first K/V tile ----
  #pragma unroll
  for (int j = 0; j < 2; j++) {
    const int chunk = (w * 2 + j) * 64 + l;
    const int r = chunk >> 3, gsrc = (chunk & 7) ^ (r & 7);
    async16(Q + (rowbase + q0 + r) * Dc + dbase + gsrc * 8,
            &QP[0][0] + (size_t)chunk * 8);
  }
  stageKV(0, 0);
  __syncthreads();
  frag qf[2];
  #pragma unroll
  for (int s = 0; s < 2; s++)
    qf[s] = *(const frag*)&QP[w * 16 + lm][(((s * 4 + lg) ^ (lm & 7))) * 8];
  // QP is dead as Q storage from here (each wave read only its own rows);
  // the same rows are reused below as this wave's P tile.

  // per-lane constants
  const float qg = (float)(q0 + w * 16 + lm);
  float koff[4][4];
  #pragma unroll
  for (int kt = 0; kt < 4; kt++)
    #pragma unroll
    for (int i = 0; i < 4; i++) koff[kt][i] = (float)(kt * 16 + lg * 4 + i);

  float m_i = -3.0e38f, l_i = 0.f;
  f32x4v acc_o[4];
  #pragma unroll
  for (int dt = 0; dt < 4; dt++) acc_o[dt] = {0.f, 0.f, 0.f, 0.f};

  int cur = 0;
  for (int k0 = 0; k0 < Lc; k0 += 64) {
    if (k0 + 64 < Lc) stageKV(cur ^ 1, k0 + 64);   // prefetch next tile

    // ---- S^T = K Q^T : rows k (64), cols q (16 of this wave) ----
    f32x4v st[4];
    #pragma unroll
    for (int kt = 0; kt < 4; kt++) st[kt] = {0.f, 0.f, 0.f, 0.f};
    __builtin_amdgcn_s_setprio(1);
    #pragma unroll
    for (int kt = 0; kt < 4; kt++) {
      #pragma unroll
      for (int s = 0; s < 2; s++) {
        frag kf = *(const frag*)&Ks[cur][kt * 16 + lm][(s * 4 + lg) ^ (lm & 7)][0];
        st[kt] = __builtin_amdgcn_mfma_f32_16x16x32_bf16(kf, qf[s], st[kt], 0, 0, 0);
      }
    }
    __builtin_amdgcn_s_setprio(0);

    // ---- bias by region (block-uniform branch) + row max ----
    const float qk0 = qg - (float)k0;
    float sv[4][4], tmax = -3.0e38f;
    if (k0 + 64 <= q0) {           // fully past: bias = sl2*(qg-kg), linear
      #pragma unroll
      for (int kt = 0; kt < 4; kt++)
        #pragma unroll
        for (int i = 0; i < 4; i++) {
          const float v = fmaf(sl2, qk0 - koff[kt][i], st[kt][i]);
          sv[kt][i] = v; tmax = fmaxf(tmax, v);
        }
    } else if (k0 <= q0) {         // diagonal tile: clamp at 0
      #pragma unroll
      for (int kt = 0; kt < 4; kt++)
        #pragma unroll
        for (int i = 0; i < 4; i++) {
          const float v = fmaf(sl2, fmaxf(qk0 - koff[kt][i], 0.f), st[kt][i]);
          sv[kt][i] = v; tmax = fmaxf(tmax, v);
        }
    } else {                       // fully future: bias = 0
      #pragma unroll
      for (int kt = 0; kt < 4; kt++)
        #pragma unroll
        for (int i = 0; i < 4; i++) {
          const float v = st[kt][i];
          sv[kt][i] = v; tmax = fmaxf(tmax, v);
        }
    }
    tmax = fmaxf(tmax, __shfl_xor(tmax, 16, 64));
    tmax = fmaxf(tmax, __shfl_xor(tmax, 32, 64));

    // ---- tile skip: contribution < 2^-27 per element -> negligible ----
    if (!__all(tmax < m_i - 27.0f)) {
      if (__any(tmax > m_i)) {     // exact skip: otherwise alpha == 1
        const float mnew = fmaxf(m_i, tmax);
        const float alpha = exp2f(m_i - mnew);
        m_i = mnew;
        l_i *= alpha;
        float aO[4];
        #pragma unroll
        for (int i = 0; i < 4; i++) aO[i] = __shfl(alpha, lg * 4 + i, 64);
        #pragma unroll
        for (int dt = 0; dt < 4; dt++)
          #pragma unroll
          for (int i = 0; i < 4; i++) acc_o[dt][i] *= aO[i];
      }
      float rsum = 0.f;
      const int qrow = w * 16 + lm;
      const int rsw = lm & 7;                       // P swizzle key (row&7)
      #pragma unroll
      for (int kt = 0; kt < 4; kt++) {
        const float p0 = exp2f(sv[kt][0] - m_i), p1 = exp2f(sv[kt][1] - m_i);
        const float p2 = exp2f(sv[kt][2] - m_i), p3 = exp2f(sv[kt][3] - m_i);
        rsum += (p0 + p1) + (p2 + p3);
        unsigned int w0, w1;       // packed bf16 pairs (lo=first arg)
        asm("v_cvt_pk_bf16_f32 %0, %1, %2" : "=v"(w0) : "v"(p0), "v"(p1));
        asm("v_cvt_pk_bf16_f32 %0, %1, %2" : "=v"(w1) : "v"(p2), "v"(p3));
        uint2 pw; pw.x = w0; pw.y = w1;
        // flat col kt*16+lg*4 -> 16B unit kt*2+(lg>>1), half (lg&1); unit^rsw
        *(uint2*)&QP[qrow][((kt * 2 + (lg >> 1)) ^ rsw) * 8 + (lg & 1) * 4] = pw;
      }
      rsum += __shfl_xor(rsum, 16, 64);
      rsum += __shfl_xor(rsum, 32, 64);
      l_i += rsum;

      // ---- O += P V (QP rows wave-private; same-wave DS order suffices) ----
      __builtin_amdgcn_s_setprio(1);
      #pragma unroll
      for (int c = 0; c < 2; c++) {
        // flat col c*32+lg*8 -> 16B unit c*4+lg; unit^rsw
        frag ap = *(const frag*)&QP[qrow][((c * 4 + lg) ^ rsw) * 8];
        #pragma unroll
        for (int dt = 0; dt < 4; dt++) {
          frag bv = *(const frag*)&Vt[cur][dt * 16 + lm][(c * 4 + lg) ^ (lm & 7)][0];
          acc_o[dt] = __builtin_amdgcn_mfma_f32_16x16x32_bf16(ap, bv, acc_o[dt], 0, 0, 0);
        }
      }
      __builtin_amdgcn_s_setprio(0);
    }

    __syncthreads();    // drains this iter's lgkm reads + next-tile vmcnt
    cur ^= 1;
  }

  // ---- epilogue: normalize, bounce through QP (swizzled), coalesced store ----
  float lO[4];
  #pragma unroll
  for (int i = 0; i < 4; i++) lO[i] = 1.0f / __shfl(l_i, lg * 4 + i, 64);
  #pragma unroll
  for (int dt = 0; dt < 4; dt++)
    #pragma unroll
    for (int i = 0; i < 4; i++) {
      const int rr = w * 16 + lg * 4 + i;
      // flat col dt*16+lm -> unit dt*2+(lm>>3), offset lm&7; unit^(rr&7)
      QP[rr][((dt * 2 + (lm >> 3)) ^ (rr & 7)) * 8 + (lm & 7)] = f2b(acc_o[dt][i] * lO[i]);
    }
  __syncthreads();
  #pragma unroll
  for (int j = 0; j < 2; j++) {
    const int chunk = (w * 2 + j) * 64 + l;
    const int r = chunk >> 3, g = chunk & 7;
    alignas(16) unsigned short tmp[8];
    #pragma unroll
    for (int t = 0; t < 8; t++) tmp[t] = QP[r][(g ^ (r & 7)) * 8 + t];
    *(uint4*)(O + (rowbase + q0 + r) * Dc + dbase + g * 8) = *(uint4*)tmp;
  }
}

// ---------- fused: mem1 = RES + ln(X;n1) -> fp32; hln = ln(mem1;cln) -> bf16 ----
__global__ __launch_bounds__(256)
void ln_res_cln_kernel(const float* __restrict__ X, const float* __restrict__ RES,
                       const float* __restrict__ g1, const float* __restrict__ b1,
                       const float* __restrict__ g2, const float* __restrict__ b2,
                       float* __restrict__ OUT1, unsigned short* __restrict__ OUT2)
{
  __shared__ float red4[4];
  const int row = blockIdx.x, tid = threadIdx.x;
  const size_t base = (size_t)row * Dc + tid * 4;
  const float4 xv = *(const float4*)(X + base);
  float s = xv.x + xv.y + xv.z + xv.w;
  s = block_sum(s, red4);
  const float mean = s * (1.0f / Dc);
  const float d0 = xv.x-mean, d1 = xv.y-mean, d2 = xv.z-mean, d3 = xv.w-mean;
  float ss = d0*d0 + d1*d1 + d2*d2 + d3*d3;
  ss = block_sum(ss, red4);
  const float rstd = rsqrtf(ss * (1.0f / Dc) + 1e-5f);
  const int c = tid * 4;
  const float4 rv = *(const float4*)(RES + base);
  float y0 = rv.x + d0*rstd*ldf(g1+c+0) + ldf(b1+c+0);
  float y1 = rv.y + d1*rstd*ldf(g1+c+1) + ldf(b1+c+1);
  float y2 = rv.z + d2*rstd*ldf(g1+c+2) + ldf(b1+c+2);
  float y3 = rv.w + d3*rstd*ldf(g1+c+3) + ldf(b1+c+3);
  *(float4*)(OUT1 + base) = make_float4(y0, y1, y2, y3);
  float s2 = y0 + y1 + y2 + y3;
  s2 = block_sum(s2, red4);
  const float mean2 = s2 * (1.0f / Dc);
  const float e0 = y0-mean2, e1 = y1-mean2, e2 = y2-mean2, e3 = y3-mean2;
  float ss2 = e0*e0 + e1*e1 + e2*e2 + e3*e3;
  ss2 = block_sum(ss2, red4);
  const float rstd2 = rsqrtf(ss2 * (1.0f / Dc) + 1e-5f);
  ushort4 o;
  o.x = f2b(e0*rstd2*ldf(g2+c+0) + ldf(b2+c+0));
  o.y = f2b(e1*rstd2*ldf(g2+c+1) + ldf(b2+c+1));
  o.z = f2b(e2*rstd2*ldf(g2+c+2) + ldf(b2+c+2));
  o.w = f2b(e3*rstd2*ldf(g2+c+3) + ldf(b2+c+3));
  *(ushort4*)(OUT2 + base) = o;
}

__global__ __launch_bounds__(256)   // OUT = ln(X + Y)
void ln_sum_kernel(const float* __restrict__ X, const float* __restrict__ Y,
                   const float* __restrict__ g, const float* __restrict__ be,
                   float* __restrict__ OUT)
{
  __shared__ float red4[4];
  const int row = blockIdx.x, tid = threadIdx.x;
  const size_t base = (size_t)row * Dc + tid * 4;
  const float4 xv = *(const float4*)(X + base);
  const float4 yv = *(const float4*)(Y + base);
  const float x0 = xv.x+yv.x, x1 = xv.y+yv.y, x2 = xv.z+yv.z, x3 = xv.w+yv.w;
  float s = x0 + x1 + x2 + x3;
  s = block_sum(s, red4);
  const float mean = s * (1.0f / Dc);
  const float d0 = x0-mean, d1 = x1-mean, d2 = x2-mean, d3 = x3-mean;
  float ss = d0*d0 + d1*d1 + d2*d2 + d3*d3;
  ss = block_sum(ss, red4);
  const float rstd = rsqrtf(ss * (1.0f / Dc) + 1e-5f);
  const int c = tid * 4;
  float4 o;
  o.x = d0*rstd*ldf(g+c+0) + ldf(be+c+0);
  o.y = d1*rstd*ldf(g+c+1) + ldf(be+c+1);
  o.z = d2*rstd*ldf(g+c+2) + ldf(be+c+2);
  o.w = d3*rstd*ldf(g+c+3) + ldf(be+c+3);
  *(float4*)(OUT + base) = o;
}

// ---------- depthwise conv K=5 with fused GLU input (+bias, bn-scale,
// hardswish), bf16 out. ----------
__global__ __launch_bounds__(256)
void dwconv_glu_bf16_kernel(const float* __restrict__ H1, const float* __restrict__ w,
                            const float* __restrict__ wb, const float* __restrict__ gn,
                            const float* __restrict__ bb, unsigned short* __restrict__ OUT)
{
  const int gid = blockIdx.x * 256 + threadIdx.x;
  const int d = gid & (Dc - 1);
  const int l = (gid >> 10) & (Lc - 1);
  const int b = gid >> 21;
  const size_t rowb = (size_t)b * Lc;
  float acc = ldf(wb + d);
  #pragma unroll
  for (int s = 0; s < 5; s++) {
    const int lp = l + 2 - s;
    if (lp >= 0 && lp < Lc) {
      const float* p = H1 + (rowb + lp) * (size_t)(2 * Dc) + d;
      const float a = p[0], g = p[Dc];
      acc += ldf(w + d * 5 + s) * (a / (1.0f + expf(-g)));
    }
  }
  const float rs = rsqrtf(1.0f + 1e-5f);
  const float t = acc * rs * ldf(gn + d) + ldf(bb + d);
  OUT[gid] = f2b(t * fminf(fmaxf(t + 3.0f, 0.0f), 6.0f) * (1.0f / 6.0f));
}

// =====================================================================
extern "C" void kernel_launch(void* const* d_in, const int* in_sizes, int n_in,
                              void* d_out, int out_size, void* d_ws, size_t ws_size,
                              hipStream_t stream) {
  (void)in_sizes; (void)n_in; (void)out_size; (void)ws_size;
  const float* mem    = (const float*)d_in[0];
  const float* wq     = (const float*)d_in[1];
  const float* bq     = (const float*)d_in[2];
  const float* wk     = (const float*)d_in[3];
  const float* bk     = (const float*)d_in[4];
  const float* wv     = (const float*)d_in[5];
  const float* bv     = (const float*)d_in[6];
  const float* wo     = (const float*)d_in[7];
  const float* bo     = (const float*)d_in[8];
  const float* n1g    = (const float*)d_in[9];
  const float* n1b    = (const float*)d_in[10];
  const float* clng   = (const float*)d_in[11];
  const float* clnb   = (const float*)d_in[12];
  const float* pw1w   = (const float*)d_in[13];
  const float* pw1b   = (const float*)d_in[14];
  const float* dww    = (const float*)d_in[15];
  const float* dwb    = (const float*)d_in[16];
  const float* bng    = (const float*)d_in[17];
  const float* bnb    = (const float*)d_in[18];
  const float* pw2w   = (const float*)d_in[19];
  const float* pw2b   = (const float*)d_in[20];
  const float* projw  = (const float*)d_in[21];
  const float* projb  = (const float*)d_in[22];
  const float* proj2w = (const float*)d_in[23];
  const float* proj2b = (const float*)d_in[24];
  const float* lin1w  = (const float*)d_in[25];
  const float* lin1b  = (const float*)d_in[26];
  const float* lin2w  = (const float*)d_in[27];
  const float* lin2b  = (const float*)d_in[28];
  const float* n3g    = (const float*)d_in[29];
  const float* n3b    = (const float*)d_in[30];
  float* out = (float*)d_out;

  char* base = (char*)d_ws;
  float* qb   = (float*)base;          // q fp32 -> tgt2 fp32
  float* kb   = qb + TD;               // k fp32 -> mem1
  float* big1 = kb + TD;               // h1 lo -> mem2 fp32
  float* big2 = big1 + TD;             // h1 hi -> conv_out
  float* ob   = big2 + TD;             // ffout
  unsigned short* abf  = (unsigned short*)(base + 5 * TD * 4);  // bf16 hub
  unsigned short* qbf  = abf + TD;     // rope-q -> mem2 bf16
  unsigned short* kbf  = qbf + TD;
  unsigned short* vtb  = kbf + TD;     // V^T bf16  [b][1024 d][2048 l]
  unsigned short* m1T  = vtb + TD;
  unsigned short* ffbbf= m1T + TD;     // NT*FF = 4*TD shorts
  unsigned short* wt   = ffbbf + 4 * TD;
  unsigned short* wqT    = wt;            // [1024][1024] } contiguous => [3072][1024] fused QKV B^T
  unsigned short* wkT    = wqT + MEG;
  unsigned short* wvT    = wkT + MEG;
  unsigned short* woT    = wvT + MEG;
  unsigned short* pw1T   = woT + MEG;     // [2048][1024]
  unsigned short* pw2T   = pw1T + 2*MEG;  // [1024][1024]
  unsigned short* proj2T = pw2T + MEG;    // [1024][1024]
  unsigned short* projwT = proj2T + MEG;  // [2048][2048]
  unsigned short* lin1T  = projwT + 4*MEG;// [4096][1024]
  unsigned short* lin2T  = lin1T + 4*MEG; // [1024][4096]
  float* pet = (float*)(lin2T + 4*MEG);   // [2048][64] rope table

  const dim3 blk(256);
  const long long LD = (long long)Lc * Dc;

  // ---- fused weight transposes + rope table ----
  TPack tp;
  const float* tin[10]  = {wq, wk, wv, wo, pw1w, pw2w, proj2w, projw, lin1w, lin2w};
  unsigned short* tout[10] = {wqT, wkT, wvT, woT, pw1T, pw2T, proj2T, projwT, lin1T, lin2T};
  const int tR[10] = {1024,1024,1024,1024,1024,1024,1024,2048,1024,4096};
  const int tC[10] = {1024,1024,1024,1024,2048,1024,1024,2048,4096,1024};
  int startAcc = 0;
  for (int i = 0; i < 10; i++) {
    tp.in[i] = tin[i]; tp.out[i] = tout[i];
    tp.R[i] = tR[i]; tp.C[i] = tC[i]; tp.tx[i] = tC[i] / 64;
    tp.start[i] = startAcc;
    startAcc += (tR[i] / 64) * (tC[i] / 64);
  }
  fused_transpose_kernel<<<dim3(startAcc), blk, 0, stream>>>(tp);
  pe_fill_kernel<<<dim3(Lc * 64 / 256), blk, 0, stream>>>(pet);

  // ---- attention ----
  convert_bf16_kernel<<<dim3((unsigned)(TD/1024)),blk,0,stream>>>(mem, abf);
  // fused QKV: N=3072, q->qb fp32, k->kb fp32, V->vtb transposed bf16 directly
  mfma_gemm_kernel<128,EPI_QKV,false,false><<<dim3(24,32,1),blk,0,stream>>>(
      abf, wqT, bq, bk, bv, nullptr, qb, vtb, NT, 3*Dc, Dc, 0, 0, 0);
  rope2_kernel<<<dim3(2*NT*Hc/256),blk,0,stream>>>(qb, kb, pet, qbf, kbf);
  flash_attn_mfma_kernel<<<dim3(1024),blk,0,stream>>>(qbf,kbf,vtb,abf);
  mfma_gemm_kernel<64,EPI_BIAS,false,false><<<dim3(8,64,1),blk,0,stream>>>(
      abf,woT,bo,nullptr,nullptr,nullptr,qb,nullptr,NT,Dc,Dc,0,0,0);
  // mem1 (fp32 -> kb) and ln(mem1) (bf16 -> abf) in one pass
  ln_res_cln_kernel<<<dim3(NT),blk,0,stream>>>(qb, mem, n1g, n1b, clng, clnb, kb, abf);

  // ---- conv block (GLU fused into dwconv) ----
  mfma_gemm_kernel<128,EPI_BIAS,false,false><<<dim3(16,32,1),blk,0,stream>>>(
      abf,pw1T,pw1b,nullptr,nullptr,nullptr,big1,nullptr,NT,2*Dc,Dc,0,0,0);
  dwconv_glu_bf16_kernel<<<dim3((unsigned)(TD/256)),blk,0,stream>>>(big1, dww, dwb, bng, bnb, abf);
  mfma_gemm_kernel<64,EPI_ADDROW0,false,false><<<dim3(8,64,1),blk,0,stream>>>(
      abf,pw2T,pw2b,nullptr,nullptr,kb,big2,nullptr,NT,Dc,Dc,0,0,0);

  // ---- proj path ----
  transpose_convert_kernel<<<dim3(16,32,2),blk,0,stream>>>(kb, m1T, 2048, 1024, LD, LD);
  mfma_gemm_kernel<64,EPI_BIAS_ROW,true,false><<<dim3(8,32,2),blk,0,stream>>>(
      projwT,m1T,projb,nullptr,nullptr,nullptr,nullptr,abf,Lc,Dc,Lc,0,LD,LD);
  // mem2 = proj@proj2 + conv_out: fp32 -> big1 AND bf16 -> qbf (feeds lin1)
  mfma_gemm_kernel<64,EPI_ADD,false,true><<<dim3(8,64,1),blk,0,stream>>>(
      abf,proj2T,proj2b,nullptr,nullptr,big2,big1,qbf,NT,Dc,Dc,0,0,0);

  // ---- feed-forward ----
  mfma_gemm_kernel<128,EPI_GELU,true,false><<<dim3(32,32,1),blk,0,stream>>>(
      qbf,lin1T,lin1b,nullptr,nullptr,nullptr,nullptr,ffbbf,NT,FFc,Dc,0,0,0);
  mfma_gemm_kernel<64,EPI_BIAS,false,false><<<dim3(8,64,1),blk,0,stream>>>(
      ffbbf,lin2T,lin2b,nullptr,nullptr,nullptr,ob,nullptr,NT,Dc,FFc,0,0,0);

  // ---- final: out = ln(mem2 + ffout) ----
  ln_sum_kernel<<<dim3(NT),blk,0,stream>>>(big1, ob, n3g, n3b, out);
}